// Round 1
// baseline (6024.546 us; speedup 1.0000x reference)
//
#include <hip/hip_runtime.h>

#define NN 100000
#define EE 3200000

// ws layout (floats):
//   h_sum   : [0, 3,200,000)   N*32
//   out_sum : [3,200,000, 3,600,000)  N*4
//   cnt     : [3,600,000, 3,700,000)  N
//   z       : [3,700,000, 3,900,000)  N*2
#define WS_HSUM   0
#define WS_OUTSUM 3200000
#define WS_CNT    3600000
#define WS_Z      3700000

__global__ __launch_bounds__(256) void enc_kernel(
    const float* __restrict__ x, const int* __restrict__ ei,
    const float* __restrict__ W1, const float* __restrict__ b1,
    const float* __restrict__ W2, const float* __restrict__ b2,
    float* __restrict__ h_sum, float* __restrict__ cnt)
{
    int e = blockIdx.x * blockDim.x + threadIdx.x;
    if (e >= EE) return;
    int s = ei[e];
    int d = ei[EE + e];
    float4 xd = *reinterpret_cast<const float4*>(x + 4 * d);
    float4 xs = *reinterpret_cast<const float4*>(x + 4 * s);
    float in8[8] = {xd.x, xd.y, xd.z, xd.w,
                    xs.x - xd.x, xs.y - xd.y, xs.z - xd.z, xs.w - xd.w};
    float h1[32];
#pragma unroll
    for (int k = 0; k < 32; ++k) {
        float a = b1[k];
#pragma unroll
        for (int j = 0; j < 8; ++j) a = fmaf(in8[j], W1[j * 32 + k], a);
        h1[k] = fmaxf(a, 0.f);
    }
#pragma unroll
    for (int k = 0; k < 32; ++k) {
        float a = b2[k];
#pragma unroll
        for (int j = 0; j < 32; ++j) a = fmaf(h1[j], W2[j * 32 + k], a);
        a = fmaxf(a, 0.f);
        atomicAdd(&h_sum[d * 32 + k], a);
    }
    atomicAdd(&cnt[d], 1.0f);
}

__global__ __launch_bounds__(256) void node_kernel(
    const float* __restrict__ h_sum, const float* __restrict__ cnt,
    const float* __restrict__ eps,
    const float* __restrict__ muW, const float* __restrict__ mub,
    const float* __restrict__ vW, const float* __restrict__ vb,
    float* __restrict__ z, float* __restrict__ out)
{
    int n = blockIdx.x * blockDim.x + threadIdx.x;
    if (n >= NN) return;
    float inv = 1.f / fmaxf(cnt[n], 1.f);
    float h[32];
#pragma unroll
    for (int k = 0; k < 32; ++k) h[k] = h_sum[n * 32 + k] * inv;
    float mu0 = mub[0], mu1 = mub[1], lv0 = vb[0], lv1 = vb[1];
#pragma unroll
    for (int k = 0; k < 32; ++k) {
        mu0 = fmaf(h[k], muW[k * 2 + 0], mu0);
        mu1 = fmaf(h[k], muW[k * 2 + 1], mu1);
        lv0 = fmaf(h[k], vW[k * 2 + 0], lv0);
        lv1 = fmaf(h[k], vW[k * 2 + 1], lv1);
    }
    float e0 = eps[n * 2 + 0], e1 = eps[n * 2 + 1];
    // d_out layout: out[N*4] | mu[N*2] | logvar[N*2]
    out[400000 + n * 2 + 0] = mu0;
    out[400000 + n * 2 + 1] = mu1;
    out[600000 + n * 2 + 0] = lv0;
    out[600000 + n * 2 + 1] = lv1;
    z[n * 2 + 0] = mu0 + e0 * __expf(0.5f * lv0);
    z[n * 2 + 1] = mu1 + e1 * __expf(0.5f * lv1);
}

__global__ __launch_bounds__(256) void dec_kernel(
    const float* __restrict__ z, const int* __restrict__ ei,
    const float* __restrict__ W1, const float* __restrict__ b1,
    const float* __restrict__ W2, const float* __restrict__ b2,
    const float* __restrict__ W3, const float* __restrict__ b3,
    float* __restrict__ out_sum)
{
    int e = blockIdx.x * blockDim.x + threadIdx.x;
    if (e >= EE) return;
    int s = ei[e];
    int d = ei[EE + e];
    float2 zd = *reinterpret_cast<const float2*>(z + 2 * d);
    float2 zs = *reinterpret_cast<const float2*>(z + 2 * s);
    float in4[4] = {zd.x, zd.y, zs.x - zd.x, zs.y - zd.y};
    float h1[32];
#pragma unroll
    for (int k = 0; k < 32; ++k) {
        float a = b1[k];
#pragma unroll
        for (int j = 0; j < 4; ++j) a = fmaf(in4[j], W1[j * 32 + k], a);
        h1[k] = fmaxf(a, 0.f);
    }
    float h2[32];
#pragma unroll
    for (int k = 0; k < 32; ++k) {
        float a = b2[k];
#pragma unroll
        for (int j = 0; j < 32; ++j) a = fmaf(h1[j], W2[j * 32 + k], a);
        h2[k] = fmaxf(a, 0.f);
    }
#pragma unroll
    for (int k = 0; k < 4; ++k) {
        float a = b3[k];
#pragma unroll
        for (int j = 0; j < 32; ++j) a = fmaf(h2[j], W3[j * 4 + k], a);
        atomicAdd(&out_sum[d * 4 + k], a);
    }
}

__global__ __launch_bounds__(256) void final_kernel(
    const float* __restrict__ out_sum, const float* __restrict__ cnt,
    float* __restrict__ out)
{
    int n = blockIdx.x * blockDim.x + threadIdx.x;
    if (n >= NN) return;
    float inv = 1.f / fmaxf(cnt[n], 1.f);
    float4 v = *reinterpret_cast<const float4*>(out_sum + 4 * n);
    float4 r;
    r.x = v.x * inv; r.y = v.y * inv; r.z = v.z * inv; r.w = v.w * inv;
    *reinterpret_cast<float4*>(out + 4 * n) = r;
}

extern "C" void kernel_launch(void* const* d_in, const int* in_sizes, int n_in,
                              void* d_out, int out_size, void* d_ws, size_t ws_size,
                              hipStream_t stream)
{
    const float* x     = (const float*)d_in[0];
    const int*   ei    = (const int*)d_in[1];
    const float* eps   = (const float*)d_in[2];
    const float* encW1 = (const float*)d_in[3];
    const float* encb1 = (const float*)d_in[4];
    const float* encW2 = (const float*)d_in[5];
    const float* encb2 = (const float*)d_in[6];
    const float* muW   = (const float*)d_in[7];
    const float* mub   = (const float*)d_in[8];
    const float* vW    = (const float*)d_in[9];
    const float* vb    = (const float*)d_in[10];
    const float* decW1 = (const float*)d_in[11];
    const float* decb1 = (const float*)d_in[12];
    const float* decW2 = (const float*)d_in[13];
    const float* decb2 = (const float*)d_in[14];
    const float* decW3 = (const float*)d_in[15];
    const float* decb3 = (const float*)d_in[16];

    float* ws      = (float*)d_ws;
    float* h_sum   = ws + WS_HSUM;
    float* out_sum = ws + WS_OUTSUM;
    float* cnt     = ws + WS_CNT;
    float* z       = ws + WS_Z;

    // zero h_sum + out_sum + cnt (contiguous prefix of ws)
    hipMemsetAsync(d_ws, 0, (size_t)WS_Z * sizeof(float), stream);

    dim3 blk(256);
    dim3 egrid((EE + 255) / 256);
    dim3 ngrid((NN + 255) / 256);

    enc_kernel<<<egrid, blk, 0, stream>>>(x, ei, encW1, encb1, encW2, encb2, h_sum, cnt);
    node_kernel<<<ngrid, blk, 0, stream>>>(h_sum, cnt, eps, muW, mub, vW, vb, z, (float*)d_out);
    dec_kernel<<<egrid, blk, 0, stream>>>(z, ei, decW1, decb1, decW2, decb2, decW3, decb3, out_sum);
    final_kernel<<<ngrid, blk, 0, stream>>>(out_sum, cnt, (float*)d_out);
}

// Round 2
// 1332.655 us; speedup vs baseline: 4.5207x; 4.5207x over previous
//
#include <hip/hip_runtime.h>

#define NN 100000
#define EE 3200000

// ws layout (4-byte units):
//   cnt    : [0,       100000)          N int
//   cursor : [100000,  200000)          N int
//   off    : [200000,  300001)          N+1 int
//   srcs   : [300032,  3500032)         E int (128B aligned)
//   z      : [3500032, 3700032)         2N float
#define WS_CNT    0
#define WS_CUR    100000
#define WS_OFF    200000
#define WS_SRCS   300032
#define WS_Z      3500032

__global__ __launch_bounds__(256) void hist_kernel(
    const int* __restrict__ ei, int* __restrict__ cnt)
{
    int e = blockIdx.x * blockDim.x + threadIdx.x;
    if (e >= EE) return;
    atomicAdd(&cnt[ei[EE + e]], 1);
}

__global__ __launch_bounds__(1024) void scan_kernel(
    const int* __restrict__ cnt, int* __restrict__ off)
{
    const int CH = 98;  // 1024*98 >= 100000
    int tid = threadIdx.x;
    int lo = tid * CH;
    int hi = lo + CH; if (hi > NN) hi = NN;
    int s = 0;
    for (int i = lo; i < hi; ++i) s += cnt[i];
    __shared__ int ls[1024];
    ls[tid] = s;
    __syncthreads();
    if (tid == 0) {
        int a = 0;
        for (int i = 0; i < 1024; ++i) { int t = ls[i]; ls[i] = a; a += t; }
    }
    __syncthreads();
    int p = ls[tid];
    for (int i = lo; i < hi; ++i) { off[i] = p; p += cnt[i]; }
    if (tid == 1023) off[NN] = p;   // empty chunk -> p == total == EE
}

__global__ __launch_bounds__(256) void scatter_kernel(
    const int* __restrict__ ei, const int* __restrict__ off,
    int* __restrict__ cursor, int* __restrict__ srcs)
{
    int e = blockIdx.x * blockDim.x + threadIdx.x;
    if (e >= EE) return;
    int s = ei[e];
    int d = ei[EE + e];
    int p = atomicAdd(&cursor[d], 1);
    srcs[off[d] + p] = s;
}

// 2 lanes per node; pair-reduce via shfl_xor(1). Fuses mean + mu/logvar/z head.
__global__ __launch_bounds__(256) void enc_gather(
    const float* __restrict__ x, const int* __restrict__ srcs,
    const int* __restrict__ off, const float* __restrict__ eps,
    const float* __restrict__ W1, const float* __restrict__ b1,
    const float* __restrict__ W2, const float* __restrict__ b2,
    const float* __restrict__ muW, const float* __restrict__ mub,
    const float* __restrict__ vW, const float* __restrict__ vb,
    float* __restrict__ z, float* __restrict__ out)
{
    int t = blockIdx.x * blockDim.x + threadIdx.x;
    int n = t >> 1;
    if (n >= NN) return;
    int half = t & 1;
    int lo = off[n], hi = off[n + 1];
    int deg = hi - lo;
    float4 xn = *reinterpret_cast<const float4*>(x + 4 * n);
    float acc[32];
#pragma unroll
    for (int k = 0; k < 32; ++k) acc[k] = 0.f;

    for (int e = lo + half; e < hi; e += 2) {
        int s = srcs[e];
        float4 xs = *reinterpret_cast<const float4*>(x + 4 * s);
        float in8[8] = {xn.x, xn.y, xn.z, xn.w,
                        xs.x - xn.x, xs.y - xn.y, xs.z - xn.z, xs.w - xn.w};
        float h1[32];
#pragma unroll
        for (int k = 0; k < 32; ++k) {
            float a = b1[k];
#pragma unroll
            for (int j = 0; j < 8; ++j) a = fmaf(in8[j], W1[j * 32 + k], a);
            h1[k] = fmaxf(a, 0.f);
        }
#pragma unroll
        for (int k = 0; k < 32; ++k) {
            float a = b2[k];
#pragma unroll
            for (int j = 0; j < 32; ++j) a = fmaf(h1[j], W2[j * 32 + k], a);
            acc[k] += fmaxf(a, 0.f);
        }
    }
#pragma unroll
    for (int k = 0; k < 32; ++k) acc[k] += __shfl_xor(acc[k], 1);

    if (half) return;
    float inv = 1.f / fmaxf((float)deg, 1.f);
    float mu0 = mub[0], mu1 = mub[1], lv0 = vb[0], lv1 = vb[1];
#pragma unroll
    for (int k = 0; k < 32; ++k) {
        float h = acc[k] * inv;
        mu0 = fmaf(h, muW[k * 2 + 0], mu0);
        mu1 = fmaf(h, muW[k * 2 + 1], mu1);
        lv0 = fmaf(h, vW[k * 2 + 0], lv0);
        lv1 = fmaf(h, vW[k * 2 + 1], lv1);
    }
    float e0 = eps[n * 2 + 0], e1 = eps[n * 2 + 1];
    // d_out layout: out[4N] | mu[2N] | logvar[2N]
    out[400000 + n * 2 + 0] = mu0;
    out[400000 + n * 2 + 1] = mu1;
    out[600000 + n * 2 + 0] = lv0;
    out[600000 + n * 2 + 1] = lv1;
    z[n * 2 + 0] = mu0 + e0 * __expf(0.5f * lv0);
    z[n * 2 + 1] = mu1 + e1 * __expf(0.5f * lv1);
}

// 2 lanes per node; decoder MLP; fuses mean + final store.
__global__ __launch_bounds__(256) void dec_gather(
    const float* __restrict__ z, const int* __restrict__ srcs,
    const int* __restrict__ off,
    const float* __restrict__ W1, const float* __restrict__ b1,
    const float* __restrict__ W2, const float* __restrict__ b2,
    const float* __restrict__ W3, const float* __restrict__ b3,
    float* __restrict__ out)
{
    int t = blockIdx.x * blockDim.x + threadIdx.x;
    int n = t >> 1;
    if (n >= NN) return;
    int half = t & 1;
    int lo = off[n], hi = off[n + 1];
    int deg = hi - lo;
    float2 zn = *reinterpret_cast<const float2*>(z + 2 * n);
    float acc[4] = {0.f, 0.f, 0.f, 0.f};

    for (int e = lo + half; e < hi; e += 2) {
        int s = srcs[e];
        float2 zs = *reinterpret_cast<const float2*>(z + 2 * s);
        float in4[4] = {zn.x, zn.y, zs.x - zn.x, zs.y - zn.y};
        float h1[32];
#pragma unroll
        for (int k = 0; k < 32; ++k) {
            float a = b1[k];
#pragma unroll
            for (int j = 0; j < 4; ++j) a = fmaf(in4[j], W1[j * 32 + k], a);
            h1[k] = fmaxf(a, 0.f);
        }
        float h2[32];
#pragma unroll
        for (int k = 0; k < 32; ++k) {
            float a = b2[k];
#pragma unroll
            for (int j = 0; j < 32; ++j) a = fmaf(h1[j], W2[j * 32 + k], a);
            h2[k] = fmaxf(a, 0.f);
        }
#pragma unroll
        for (int k = 0; k < 4; ++k) {
            float a = b3[k];
#pragma unroll
            for (int j = 0; j < 32; ++j) a = fmaf(h2[j], W3[j * 4 + k], a);
            acc[k] += a;
        }
    }
#pragma unroll
    for (int k = 0; k < 4; ++k) acc[k] += __shfl_xor(acc[k], 1);

    if (half) return;
    float inv = 1.f / fmaxf((float)deg, 1.f);
    float4 r;
    r.x = acc[0] * inv; r.y = acc[1] * inv; r.z = acc[2] * inv; r.w = acc[3] * inv;
    *reinterpret_cast<float4*>(out + 4 * n) = r;
}

extern "C" void kernel_launch(void* const* d_in, const int* in_sizes, int n_in,
                              void* d_out, int out_size, void* d_ws, size_t ws_size,
                              hipStream_t stream)
{
    const float* x     = (const float*)d_in[0];
    const int*   ei    = (const int*)d_in[1];
    const float* eps   = (const float*)d_in[2];
    const float* encW1 = (const float*)d_in[3];
    const float* encb1 = (const float*)d_in[4];
    const float* encW2 = (const float*)d_in[5];
    const float* encb2 = (const float*)d_in[6];
    const float* muW   = (const float*)d_in[7];
    const float* mub   = (const float*)d_in[8];
    const float* vW    = (const float*)d_in[9];
    const float* vb    = (const float*)d_in[10];
    const float* decW1 = (const float*)d_in[11];
    const float* decb1 = (const float*)d_in[12];
    const float* decW2 = (const float*)d_in[13];
    const float* decb2 = (const float*)d_in[14];
    const float* decW3 = (const float*)d_in[15];
    const float* decb3 = (const float*)d_in[16];

    int*   wsI    = (int*)d_ws;
    float* wsF    = (float*)d_ws;
    int*   cnt    = wsI + WS_CNT;
    int*   cursor = wsI + WS_CUR;
    int*   off    = wsI + WS_OFF;
    int*   srcs   = wsI + WS_SRCS;
    float* z      = wsF + WS_Z;

    // zero cnt + cursor
    hipMemsetAsync(d_ws, 0, (size_t)200000 * sizeof(int), stream);

    dim3 blk(256);
    dim3 egrid((EE + 255) / 256);
    dim3 ngrid2((2 * NN + 255) / 256);

    hist_kernel<<<egrid, blk, 0, stream>>>(ei, cnt);
    scan_kernel<<<dim3(1), dim3(1024), 0, stream>>>(cnt, off);
    scatter_kernel<<<egrid, blk, 0, stream>>>(ei, off, cursor, srcs);
    enc_gather<<<ngrid2, blk, 0, stream>>>(x, srcs, off, eps,
                                           encW1, encb1, encW2, encb2,
                                           muW, mub, vW, vb, z, (float*)d_out);
    dec_gather<<<ngrid2, blk, 0, stream>>>(z, srcs, off,
                                           decW1, decb1, decW2, decb2, decW3, decb3,
                                           (float*)d_out);
}

// Round 3
// 816.212 us; speedup vs baseline: 7.3811x; 1.6327x over previous
//
#include <hip/hip_runtime.h>

#define NN 100000
#define EE 3200000

// ws layout (4-byte units):
//   cnt    : [0,       100000)          N int
//   cursor : [100000,  200000)          N int
//   off    : [200000,  300001) pad->300032   N+1 int
//   srcs   : [300032,  3500032)         E int
//   h_sum  : [3500032, 6700032)         N*32 float
//   out_sum: [6700032, 7100032)         N*4 float
//   z      : [7100032, 7300032)         N*2 float
#define WS_CNT    0
#define WS_CUR    100000
#define WS_OFF    200000
#define WS_SRCS   300032
#define WS_HSUM   3500032
#define WS_OUTSUM 6700032
#define WS_Z      7100032

__global__ __launch_bounds__(256) void hist_kernel(
    const int* __restrict__ ei, int* __restrict__ cnt)
{
    int e = blockIdx.x * blockDim.x + threadIdx.x;
    if (e >= EE) return;
    atomicAdd(&cnt[ei[EE + e]], 1);
}

__global__ __launch_bounds__(1024) void scan_kernel(
    const int* __restrict__ cnt, int* __restrict__ off)
{
    const int CH = 98;  // 1024*98 >= 100000
    int tid = threadIdx.x;
    int lo = tid * CH;
    int hi = lo + CH; if (hi > NN) hi = NN;
    int s = 0;
    for (int i = lo; i < hi; ++i) s += cnt[i];
    __shared__ int ls[1024];
    ls[tid] = s;
    __syncthreads();
    if (tid == 0) {
        int a = 0;
        for (int i = 0; i < 1024; ++i) { int t = ls[i]; ls[i] = a; a += t; }
    }
    __syncthreads();
    int p = ls[tid];
    for (int i = lo; i < hi; ++i) { off[i] = p; p += cnt[i]; }
    if (tid == 1023) off[NN] = p;
}

__global__ __launch_bounds__(256) void scatter_kernel(
    const int* __restrict__ ei, const int* __restrict__ off,
    int* __restrict__ cursor, int* __restrict__ srcs)
{
    int e = blockIdx.x * blockDim.x + threadIdx.x;
    if (e >= EE) return;
    int s = ei[e];
    int d = ei[EE + e];
    int p = atomicAdd(&cursor[d], 1);
    srcs[off[d] + p] = s;
}

// Edge-parallel encoder: 1 thread = 1 edge (CSR order). Wave-segmented
// reduction via LDS transpose; one atomicAdd per (segment,channel).
__global__ __launch_bounds__(256) void enc_edge(
    const float* __restrict__ x, const int* __restrict__ srcs,
    const int* __restrict__ off,
    const float* __restrict__ W1, const float* __restrict__ b1,
    const float* __restrict__ W2, const float* __restrict__ b2,
    float* __restrict__ h_sum)
{
    __shared__ float sm[4][64][33];
    __shared__ int   sd[4][64];
    int e = blockIdx.x * blockDim.x + threadIdx.x;   // grid exact: EE threads
    int lane = threadIdx.x & 63;
    int w = threadIdx.x >> 6;

    // binary search: d such that off[d] <= e < off[d+1]
    int lo = 0, hi = NN;
    while (hi - lo > 1) { int mid = (lo + hi) >> 1; if (off[mid] <= e) lo = mid; else hi = mid; }
    int d = lo;
    int s = srcs[e];

    float4 xd = *reinterpret_cast<const float4*>(x + 4 * d);
    float4 xs = *reinterpret_cast<const float4*>(x + 4 * s);
    float in8[8] = {xd.x, xd.y, xd.z, xd.w,
                    xs.x - xd.x, xs.y - xd.y, xs.z - xd.z, xs.w - xd.w};
    float h1[32];
#pragma unroll
    for (int k = 0; k < 32; ++k) {
        float a = b1[k];
#pragma unroll
        for (int j = 0; j < 8; ++j) a = fmaf(in8[j], W1[j * 32 + k], a);
        h1[k] = fmaxf(a, 0.f);
    }
    sd[w][lane] = d;
#pragma unroll
    for (int k = 0; k < 32; ++k) {
        float a = b2[k];
#pragma unroll
        for (int j = 0; j < 32; ++j) a = fmaf(h1[j], W2[j * 32 + k], a);
        sm[w][lane][k] = fmaxf(a, 0.f);
    }
    __syncthreads();

    // lanes: channel c = lane&31, half h = lane>>5 sums rows h*32..h*32+31
    int c = lane & 31;
    int r0 = (lane >> 5) * 32;
    float acc = 0.f;
    int cur = sd[w][r0];
    for (int r = r0; r < r0 + 32; ++r) {
        int dr = sd[w][r];
        if (dr != cur) { atomicAdd(&h_sum[cur * 32 + c], acc); acc = 0.f; cur = dr; }
        acc += sm[w][r][c];
    }
    atomicAdd(&h_sum[cur * 32 + c], acc);
}

__global__ __launch_bounds__(256) void node_kernel(
    const float* __restrict__ h_sum, const int* __restrict__ off,
    const float* __restrict__ eps,
    const float* __restrict__ muW, const float* __restrict__ mub,
    const float* __restrict__ vW, const float* __restrict__ vb,
    float* __restrict__ z, float* __restrict__ out)
{
    int n = blockIdx.x * blockDim.x + threadIdx.x;
    if (n >= NN) return;
    float deg = (float)(off[n + 1] - off[n]);
    float inv = 1.f / fmaxf(deg, 1.f);
    float mu0 = mub[0], mu1 = mub[1], lv0 = vb[0], lv1 = vb[1];
#pragma unroll
    for (int k = 0; k < 32; ++k) {
        float h = h_sum[n * 32 + k] * inv;
        mu0 = fmaf(h, muW[k * 2 + 0], mu0);
        mu1 = fmaf(h, muW[k * 2 + 1], mu1);
        lv0 = fmaf(h, vW[k * 2 + 0], lv0);
        lv1 = fmaf(h, vW[k * 2 + 1], lv1);
    }
    float e0 = eps[n * 2 + 0], e1 = eps[n * 2 + 1];
    // d_out layout: out[4N] | mu[2N] | logvar[2N]
    out[400000 + n * 2 + 0] = mu0;
    out[400000 + n * 2 + 1] = mu1;
    out[600000 + n * 2 + 0] = lv0;
    out[600000 + n * 2 + 1] = lv1;
    z[n * 2 + 0] = mu0 + e0 * __expf(0.5f * lv0);
    z[n * 2 + 1] = mu1 + e1 * __expf(0.5f * lv1);
}

// Edge-parallel decoder.
__global__ __launch_bounds__(256) void dec_edge(
    const float* __restrict__ z, const int* __restrict__ srcs,
    const int* __restrict__ off,
    const float* __restrict__ W1, const float* __restrict__ b1,
    const float* __restrict__ W2, const float* __restrict__ b2,
    const float* __restrict__ W3, const float* __restrict__ b3,
    float* __restrict__ out_sum)
{
    __shared__ float sm[4][64][5];
    __shared__ int   sd[4][64];
    int e = blockIdx.x * blockDim.x + threadIdx.x;
    int lane = threadIdx.x & 63;
    int w = threadIdx.x >> 6;

    int lo = 0, hi = NN;
    while (hi - lo > 1) { int mid = (lo + hi) >> 1; if (off[mid] <= e) lo = mid; else hi = mid; }
    int d = lo;
    int s = srcs[e];

    float2 zd = *reinterpret_cast<const float2*>(z + 2 * d);
    float2 zs = *reinterpret_cast<const float2*>(z + 2 * s);
    float in4[4] = {zd.x, zd.y, zs.x - zd.x, zs.y - zd.y};
    float h1[32];
#pragma unroll
    for (int k = 0; k < 32; ++k) {
        float a = b1[k];
#pragma unroll
        for (int j = 0; j < 4; ++j) a = fmaf(in4[j], W1[j * 32 + k], a);
        h1[k] = fmaxf(a, 0.f);
    }
    float h2[32];
#pragma unroll
    for (int k = 0; k < 32; ++k) {
        float a = b2[k];
#pragma unroll
        for (int j = 0; j < 32; ++j) a = fmaf(h1[j], W2[j * 32 + k], a);
        h2[k] = fmaxf(a, 0.f);
    }
    sd[w][lane] = d;
#pragma unroll
    for (int k = 0; k < 4; ++k) {
        float a = b3[k];
#pragma unroll
        for (int j = 0; j < 32; ++j) a = fmaf(h2[j], W3[j * 4 + k], a);
        sm[w][lane][k] = a;
    }
    __syncthreads();

    // 16 lanes: channel c = lane&3, quarter q = lane>>2 sums rows q*16..+16
    if (lane < 16) {
        int c = lane & 3;
        int r0 = (lane >> 2) * 16;
        float acc = 0.f;
        int cur = sd[w][r0];
        for (int r = r0; r < r0 + 16; ++r) {
            int dr = sd[w][r];
            if (dr != cur) { atomicAdd(&out_sum[cur * 4 + c], acc); acc = 0.f; cur = dr; }
            acc += sm[w][r][c];
        }
        atomicAdd(&out_sum[cur * 4 + c], acc);
    }
}

__global__ __launch_bounds__(256) void final_kernel(
    const float* __restrict__ out_sum, const int* __restrict__ off,
    float* __restrict__ out)
{
    int n = blockIdx.x * blockDim.x + threadIdx.x;
    if (n >= NN) return;
    float deg = (float)(off[n + 1] - off[n]);
    float inv = 1.f / fmaxf(deg, 1.f);
    float4 v = *reinterpret_cast<const float4*>(out_sum + 4 * n);
    float4 r;
    r.x = v.x * inv; r.y = v.y * inv; r.z = v.z * inv; r.w = v.w * inv;
    *reinterpret_cast<float4*>(out + 4 * n) = r;
}

extern "C" void kernel_launch(void* const* d_in, const int* in_sizes, int n_in,
                              void* d_out, int out_size, void* d_ws, size_t ws_size,
                              hipStream_t stream)
{
    const float* x     = (const float*)d_in[0];
    const int*   ei    = (const int*)d_in[1];
    const float* eps   = (const float*)d_in[2];
    const float* encW1 = (const float*)d_in[3];
    const float* encb1 = (const float*)d_in[4];
    const float* encW2 = (const float*)d_in[5];
    const float* encb2 = (const float*)d_in[6];
    const float* muW   = (const float*)d_in[7];
    const float* mub   = (const float*)d_in[8];
    const float* vW    = (const float*)d_in[9];
    const float* vb    = (const float*)d_in[10];
    const float* decW1 = (const float*)d_in[11];
    const float* decb1 = (const float*)d_in[12];
    const float* decW2 = (const float*)d_in[13];
    const float* decb2 = (const float*)d_in[14];
    const float* decW3 = (const float*)d_in[15];
    const float* decb3 = (const float*)d_in[16];

    int*   wsI    = (int*)d_ws;
    float* wsF    = (float*)d_ws;
    int*   cnt    = wsI + WS_CNT;
    int*   cursor = wsI + WS_CUR;
    int*   off    = wsI + WS_OFF;
    int*   srcs   = wsI + WS_SRCS;
    float* h_sum  = wsF + WS_HSUM;
    float* out_sum= wsF + WS_OUTSUM;
    float* z      = wsF + WS_Z;

    // zero cnt+cursor, and h_sum+out_sum accumulators
    hipMemsetAsync(wsI, 0, (size_t)200000 * sizeof(int), stream);
    hipMemsetAsync(wsF + WS_HSUM, 0, (size_t)(WS_Z - WS_HSUM) * sizeof(float), stream);

    dim3 blk(256);
    dim3 egrid((EE + 255) / 256);   // 12500 exact
    dim3 ngrid((NN + 255) / 256);

    hist_kernel<<<egrid, blk, 0, stream>>>(ei, cnt);
    scan_kernel<<<dim3(1), dim3(1024), 0, stream>>>(cnt, off);
    scatter_kernel<<<egrid, blk, 0, stream>>>(ei, off, cursor, srcs);
    enc_edge<<<egrid, blk, 0, stream>>>(x, srcs, off, encW1, encb1, encW2, encb2, h_sum);
    node_kernel<<<ngrid, blk, 0, stream>>>(h_sum, off, eps, muW, mub, vW, vb, z, (float*)d_out);
    dec_edge<<<egrid, blk, 0, stream>>>(z, srcs, off, decW1, decb1, decW2, decb2, decW3, decb3, out_sum);
    final_kernel<<<ngrid, blk, 0, stream>>>(out_sum, off, (float*)d_out);
}

// Round 4
// 602.684 us; speedup vs baseline: 9.9962x; 1.3543x over previous
//
#include <hip/hip_runtime.h>
#include <hip/hip_bf16.h>

#define NN 100000
#define EE 3200000

typedef short bf16x8 __attribute__((ext_vector_type(8)));
typedef short s16x4  __attribute__((ext_vector_type(4)));
typedef float f32x16 __attribute__((ext_vector_type(16)));

// ws layout (4-byte units), total ~24 MB:
#define WS_SRCS 0            // int[EE]
#define WS_TMP  3200000      // ushort[EE] (1.6M ints)
#define WS_OFF  4800000      // int[NN+1]
#define WS_CNT  4900032      // int[NN]; grp[50000] overlays after scan
#define WS_H4   5000032      // float[NN*4]
#define WS_OUT4 5400032      // float[NN*4]
#define WS_Z    5800032      // float[NN*2]
#define WS_ZERO_BEGIN 4900032
#define WS_ZERO_COUNT 900000  // cnt + h4 + out4

static __device__ __forceinline__ short f2bf(float f) {
    __hip_bfloat16 b = __float2bfloat16(f);
    return __builtin_bit_cast(short, b);
}

__global__ __launch_bounds__(256) void rank_kernel(
    const int* __restrict__ ei, int* __restrict__ cnt, unsigned short* __restrict__ tmp)
{
    int e = blockIdx.x * 256 + threadIdx.x;   // grid exact
    int d = ei[EE + e];
    tmp[e] = (unsigned short)atomicAdd(&cnt[d], 1);
}

__global__ __launch_bounds__(1024) void scan_kernel(
    const int* __restrict__ cnt, int* __restrict__ off)
{
    const int CH = 98;   // 1024*98 >= NN
    __shared__ int ls[1024];
    int t = threadIdx.x;
    int lo = t * CH;
    int hi = lo + CH; if (hi > NN) hi = NN; if (lo > NN) lo = NN;
    int s = 0;
    for (int i = lo; i < hi; ++i) s += cnt[i];
    ls[t] = s;
    __syncthreads();
    for (int d = 1; d < 1024; d <<= 1) {
        int v = (t >= d) ? ls[t - d] : 0;
        __syncthreads();
        ls[t] += v;
        __syncthreads();
    }
    int p = ls[t] - s;   // exclusive prefix
    for (int i = lo; i < hi; ++i) { off[i] = p; p += cnt[i]; }
    if (t == 1023) off[NN] = ls[1023];   // == EE
}

__global__ __launch_bounds__(256) void place_kernel(
    const int* __restrict__ ei, const int* __restrict__ off,
    const unsigned short* __restrict__ tmp,
    int* __restrict__ srcs, int* __restrict__ grp)
{
    int e = blockIdx.x * 256 + threadIdx.x;
    int s = ei[e], d = ei[EE + e];
    int p = off[d] + (int)tmp[e];
    srcs[p] = s;
    if ((p & 63) == 0) grp[p >> 6] = d;
}

// One wave = 64 CSR-consecutive edges = two 32-edge M-tiles.
// layer1 (K1-pad-16 MFMA) -> LDS T -> layer2 (2x K16 MFMA) -> LDS T ->
// linear head 32->4 (2x K16 MFMA) -> per-lane run-merge + atomicAdd into agg4.
__global__ __launch_bounds__(256) void edge_mfma(
    const float* __restrict__ feat, int fdim,                     // 4 (enc/x) or 2 (dec/z)
    const float* __restrict__ W1, const float* __restrict__ b1,   // [2*fdim][32]
    const float* __restrict__ W2, const float* __restrict__ b2,   // [32][32]
    const float* __restrict__ hA, const float* __restrict__ hB, int hmode,
    const int* __restrict__ srcs, const int* __restrict__ off, const int* __restrict__ grp,
    float* __restrict__ agg4)
{
    __shared__ short sm[4][64][68];   // bf16, stride 68 (136B rows, 8B aligned)
    int tid = threadIdx.x;
    int w = tid >> 6, l = tid & 63;
    int j = l & 31, h = l >> 5;
    int gw = blockIdx.x * 4 + w;      // global wave id, < 50000
    int ebase = gw * 64;
    int K1 = 2 * fdim;

    // ---- B fragments (per-lane constants) ----
    bf16x8 bL1, bk0, bk1, hb0, hb1;
#pragma unroll
    for (int i = 0; i < 8; ++i) {
        bL1[i] = (h == 0 && i < K1) ? f2bf(W1[i * 32 + j]) : (short)0;
        int k0 = 8 * h + i, k1 = 16 + 8 * h + i;
        bk0[i] = f2bf(W2[k0 * 32 + j]);
        bk1[i] = f2bf(W2[k1 * 32 + j]);
        short w0 = 0, w1 = 0;
        if (j < 4) {
            if (hmode == 0) {   // enc: hA=muW [32][2], hB=vW [32][2]
                w0 = (j < 2) ? f2bf(hA[k0 * 2 + j]) : f2bf(hB[k0 * 2 + (j - 2)]);
                w1 = (j < 2) ? f2bf(hA[k1 * 2 + j]) : f2bf(hB[k1 * 2 + (j - 2)]);
            } else {            // dec: hA=W3 [32][4]
                w0 = f2bf(hA[k0 * 4 + j]);
                w1 = f2bf(hA[k1 * 4 + j]);
            }
        }
        hb0[i] = w0; hb1[i] = w1;
    }
    float bias1 = b1[j], bias2 = b2[j];

    // ---- input A-fragments: lanes h==0 hold k=0..7 (= [x_i, x_j-x_i]), h==1 zero ----
    bf16x8 aIn0 = {0,0,0,0,0,0,0,0}, aIn1 = {0,0,0,0,0,0,0,0};
    if (h == 0) {
        int e0 = ebase + j, e1 = e0 + 32;
        int n = grp[gw];
        while (off[n + 1] <= e0) ++n;
        int d0 = n;
        while (off[n + 1] <= e1) ++n;
        int d1 = n;
        int s0 = srcs[e0], s1 = srcs[e1];
        if (fdim == 4) {
            float4 xd = *(const float4*)(feat + 4 * d0);
            float4 xs = *(const float4*)(feat + 4 * s0);
            aIn0[0] = f2bf(xd.x); aIn0[1] = f2bf(xd.y);
            aIn0[2] = f2bf(xd.z); aIn0[3] = f2bf(xd.w);
            aIn0[4] = f2bf(xs.x - xd.x); aIn0[5] = f2bf(xs.y - xd.y);
            aIn0[6] = f2bf(xs.z - xd.z); aIn0[7] = f2bf(xs.w - xd.w);
            xd = *(const float4*)(feat + 4 * d1);
            xs = *(const float4*)(feat + 4 * s1);
            aIn1[0] = f2bf(xd.x); aIn1[1] = f2bf(xd.y);
            aIn1[2] = f2bf(xd.z); aIn1[3] = f2bf(xd.w);
            aIn1[4] = f2bf(xs.x - xd.x); aIn1[5] = f2bf(xs.y - xd.y);
            aIn1[6] = f2bf(xs.z - xd.z); aIn1[7] = f2bf(xs.w - xd.w);
        } else {
            float2 zd = *(const float2*)(feat + 2 * d0);
            float2 zs = *(const float2*)(feat + 2 * s0);
            aIn0[0] = f2bf(zd.x); aIn0[1] = f2bf(zd.y);
            aIn0[2] = f2bf(zs.x - zd.x); aIn0[3] = f2bf(zs.y - zd.y);
            zd = *(const float2*)(feat + 2 * d1);
            zs = *(const float2*)(feat + 2 * s1);
            aIn1[0] = f2bf(zd.x); aIn1[1] = f2bf(zd.y);
            aIn1[2] = f2bf(zs.x - zd.x); aIn1[3] = f2bf(zs.y - zd.y);
        }
    }

    f32x16 czero = {0.f,0.f,0.f,0.f,0.f,0.f,0.f,0.f,0.f,0.f,0.f,0.f,0.f,0.f,0.f,0.f};

    // ---- layer 1 ----
    f32x16 p0 = __builtin_amdgcn_mfma_f32_32x32x16_bf16(aIn0, bL1, czero, 0, 0, 0);
    f32x16 p1 = __builtin_amdgcn_mfma_f32_32x32x16_bf16(aIn1, bL1, czero, 0, 0, 0);
#pragma unroll
    for (int r = 0; r < 16; ++r) {
        int row = (r & 3) + 8 * (r >> 2) + 4 * h;
        sm[w][row][j]      = f2bf(fmaxf(p0[r] + bias1, 0.f));
        sm[w][row + 32][j] = f2bf(fmaxf(p1[r] + bias1, 0.f));
    }
    __syncthreads();

    // ---- transpose read: layer-2 A frags ----
    s16x4 q0 = *(const s16x4*)&sm[w][j][8 * h];
    s16x4 q1 = *(const s16x4*)&sm[w][j][8 * h + 4];
    s16x4 q2 = *(const s16x4*)&sm[w][j][16 + 8 * h];
    s16x4 q3 = *(const s16x4*)&sm[w][j][16 + 8 * h + 4];
    s16x4 q4 = *(const s16x4*)&sm[w][32 + j][8 * h];
    s16x4 q5 = *(const s16x4*)&sm[w][32 + j][8 * h + 4];
    s16x4 q6 = *(const s16x4*)&sm[w][32 + j][16 + 8 * h];
    s16x4 q7 = *(const s16x4*)&sm[w][32 + j][16 + 8 * h + 4];
    bf16x8 a0k0 = {q0[0],q0[1],q0[2],q0[3],q1[0],q1[1],q1[2],q1[3]};
    bf16x8 a0k1 = {q2[0],q2[1],q2[2],q2[3],q3[0],q3[1],q3[2],q3[3]};
    bf16x8 a1k0 = {q4[0],q4[1],q4[2],q4[3],q5[0],q5[1],q5[2],q5[3]};
    bf16x8 a1k1 = {q6[0],q6[1],q6[2],q6[3],q7[0],q7[1],q7[2],q7[3]};

    // ---- layer 2 ----
    f32x16 acc0 = czero, acc1 = czero;
    acc0 = __builtin_amdgcn_mfma_f32_32x32x16_bf16(a0k0, bk0, acc0, 0, 0, 0);
    acc0 = __builtin_amdgcn_mfma_f32_32x32x16_bf16(a0k1, bk1, acc0, 0, 0, 0);
    acc1 = __builtin_amdgcn_mfma_f32_32x32x16_bf16(a1k0, bk0, acc1, 0, 0, 0);
    acc1 = __builtin_amdgcn_mfma_f32_32x32x16_bf16(a1k1, bk1, acc1, 0, 0, 0);
    __syncthreads();   // all T1 reads done before overwriting sm

#pragma unroll
    for (int r = 0; r < 16; ++r) {
        int row = (r & 3) + 8 * (r >> 2) + 4 * h;
        sm[w][row][j]      = f2bf(fmaxf(acc0[r] + bias2, 0.f));
        sm[w][row + 32][j] = f2bf(fmaxf(acc1[r] + bias2, 0.f));
    }
    __syncthreads();

    // ---- transpose read: head A frags ----
    q0 = *(const s16x4*)&sm[w][j][8 * h];
    q1 = *(const s16x4*)&sm[w][j][8 * h + 4];
    q2 = *(const s16x4*)&sm[w][j][16 + 8 * h];
    q3 = *(const s16x4*)&sm[w][j][16 + 8 * h + 4];
    q4 = *(const s16x4*)&sm[w][32 + j][8 * h];
    q5 = *(const s16x4*)&sm[w][32 + j][8 * h + 4];
    q6 = *(const s16x4*)&sm[w][32 + j][16 + 8 * h];
    q7 = *(const s16x4*)&sm[w][32 + j][16 + 8 * h + 4];
    bf16x8 m0k0 = {q0[0],q0[1],q0[2],q0[3],q1[0],q1[1],q1[2],q1[3]};
    bf16x8 m0k1 = {q2[0],q2[1],q2[2],q2[3],q3[0],q3[1],q3[2],q3[3]};
    bf16x8 m1k0 = {q4[0],q4[1],q4[2],q4[3],q5[0],q5[1],q5[2],q5[3]};
    bf16x8 m1k1 = {q6[0],q6[1],q6[2],q6[3],q7[0],q7[1],q7[2],q7[3]};

    // ---- head 32->4 (linear; mean applied post-aggregation) ----
    f32x16 hc0 = czero, hc1 = czero;
    hc0 = __builtin_amdgcn_mfma_f32_32x32x16_bf16(m0k0, hb0, hc0, 0, 0, 0);
    hc0 = __builtin_amdgcn_mfma_f32_32x32x16_bf16(m0k1, hb1, hc0, 0, 0, 0);
    hc1 = __builtin_amdgcn_mfma_f32_32x32x16_bf16(m1k0, hb0, hc1, 0, 0, 0);
    hc1 = __builtin_amdgcn_mfma_f32_32x32x16_bf16(m1k1, hb1, hc1, 0, 0, 0);

    // ---- segmented flush: lanes j<4 own channel j; rows ascend with reg ----
    if (j < 4) {
        int n = grp[gw];
        int nend = off[n + 1];
        float acc = 0.f;
#pragma unroll
        for (int r = 0; r < 16; ++r) {
            int e = ebase + (r & 3) + 8 * (r >> 2) + 4 * h;
            while (e >= nend) {
                if (acc != 0.f) { atomicAdd(&agg4[n * 4 + j], acc); acc = 0.f; }
                ++n; nend = off[n + 1];
            }
            acc += hc0[r];
        }
#pragma unroll
        for (int r = 0; r < 16; ++r) {
            int e = ebase + 32 + (r & 3) + 8 * (r >> 2) + 4 * h;
            while (e >= nend) {
                if (acc != 0.f) { atomicAdd(&agg4[n * 4 + j], acc); acc = 0.f; }
                ++n; nend = off[n + 1];
            }
            acc += hc1[r];
        }
        if (acc != 0.f) atomicAdd(&agg4[n * 4 + j], acc);
    }
}

__global__ __launch_bounds__(256) void node_kernel(
    const float* __restrict__ h4, const int* __restrict__ off,
    const float* __restrict__ eps,
    const float* __restrict__ mub, const float* __restrict__ vb,
    float* __restrict__ z, float* __restrict__ out)
{
    int n = blockIdx.x * 256 + threadIdx.x;
    if (n >= NN) return;
    float inv = 1.f / fmaxf((float)(off[n + 1] - off[n]), 1.f);
    float4 a = *(const float4*)(h4 + 4 * n);
    float mu0 = a.x * inv + mub[0], mu1 = a.y * inv + mub[1];
    float lv0 = a.z * inv + vb[0],  lv1 = a.w * inv + vb[1];
    out[4 * NN + 2 * n]     = mu0;
    out[4 * NN + 2 * n + 1] = mu1;
    out[6 * NN + 2 * n]     = lv0;
    out[6 * NN + 2 * n + 1] = lv1;
    float2 zz;
    zz.x = mu0 + eps[2 * n]     * expf(0.5f * lv0);
    zz.y = mu1 + eps[2 * n + 1] * expf(0.5f * lv1);
    *(float2*)(z + 2 * n) = zz;
}

__global__ __launch_bounds__(256) void final_kernel(
    const float* __restrict__ o4, const int* __restrict__ off,
    const float* __restrict__ b3, float* __restrict__ out)
{
    int n = blockIdx.x * 256 + threadIdx.x;
    if (n >= NN) return;
    float inv = 1.f / fmaxf((float)(off[n + 1] - off[n]), 1.f);
    float4 a = *(const float4*)(o4 + 4 * n);
    float4 r;
    r.x = a.x * inv + b3[0]; r.y = a.y * inv + b3[1];
    r.z = a.z * inv + b3[2]; r.w = a.w * inv + b3[3];
    *(float4*)(out + 4 * n) = r;
}

extern "C" void kernel_launch(void* const* d_in, const int* in_sizes, int n_in,
                              void* d_out, int out_size, void* d_ws, size_t ws_size,
                              hipStream_t stream)
{
    const float* x     = (const float*)d_in[0];
    const int*   ei    = (const int*)d_in[1];
    const float* eps   = (const float*)d_in[2];
    const float* encW1 = (const float*)d_in[3];
    const float* encb1 = (const float*)d_in[4];
    const float* encW2 = (const float*)d_in[5];
    const float* encb2 = (const float*)d_in[6];
    const float* muW   = (const float*)d_in[7];
    const float* mub   = (const float*)d_in[8];
    const float* vW    = (const float*)d_in[9];
    const float* vb    = (const float*)d_in[10];
    const float* decW1 = (const float*)d_in[11];
    const float* decb1 = (const float*)d_in[12];
    const float* decW2 = (const float*)d_in[13];
    const float* decb2 = (const float*)d_in[14];
    const float* decW3 = (const float*)d_in[15];
    const float* decb3 = (const float*)d_in[16];

    int*   wsI  = (int*)d_ws;
    float* wsF  = (float*)d_ws;
    int*   srcs = wsI + WS_SRCS;
    unsigned short* tmp = (unsigned short*)(wsI + WS_TMP);
    int*   off  = wsI + WS_OFF;
    int*   cnt  = wsI + WS_CNT;
    int*   grp  = wsI + WS_CNT;       // overlays cnt (dead after scan)
    float* h4   = wsF + WS_H4;
    float* out4 = wsF + WS_OUT4;
    float* z    = wsF + WS_Z;

    hipMemsetAsync(wsI + WS_ZERO_BEGIN, 0, (size_t)WS_ZERO_COUNT * 4, stream);

    dim3 blk(256);
    dim3 egrid(12500);
    dim3 ngrid((NN + 255) / 256);

    rank_kernel<<<egrid, blk, 0, stream>>>(ei, cnt, tmp);
    scan_kernel<<<dim3(1), dim3(1024), 0, stream>>>(cnt, off);
    place_kernel<<<egrid, blk, 0, stream>>>(ei, off, tmp, srcs, grp);
    edge_mfma<<<egrid, blk, 0, stream>>>(x, 4, encW1, encb1, encW2, encb2,
                                         muW, vW, 0, srcs, off, grp, h4);
    node_kernel<<<ngrid, blk, 0, stream>>>(h4, off, eps, mub, vb, z, (float*)d_out);
    edge_mfma<<<egrid, blk, 0, stream>>>(z, 2, decW1, decb1, decW2, decb2,
                                         decW3, decW3, 1, srcs, off, grp, out4);
    final_kernel<<<ngrid, blk, 0, stream>>>(out4, off, decb3, (float*)d_out);
}

// Round 5
// 450.426 us; speedup vs baseline: 13.3752x; 1.3380x over previous
//
#include <hip/hip_runtime.h>
#include <hip/hip_bf16.h>

#define NN 100000
#define EE 3200000

typedef short bf16x8 __attribute__((ext_vector_type(8)));
typedef short s16x4  __attribute__((ext_vector_type(4)));
typedef float f32x16 __attribute__((ext_vector_type(16)));

// ws layout (4-byte units), total ~24 MB:
#define WS_SRCS 0            // int[EE]
#define WS_TMP  3200000      // ushort[EE] (1.6M ints)
#define WS_OFF  4800000      // int[NN+1]
#define WS_CNT  4900032      // int[NN]; grp[50000] overlays after scan
#define WS_H4   5000032      // float[NN*4]
#define WS_OUT4 5400032      // float[NN*4]
#define WS_Z    5800032      // float[NN*2]
#define WS_PART 6000032      // int[128]
#define WS_ZERO_BEGIN 4900032
#define WS_ZERO_COUNT 900000  // cnt + h4 + out4

static __device__ __forceinline__ short f2bf(float f) {
    __hip_bfloat16 b = __float2bfloat16(f);
    return __builtin_bit_cast(short, b);
}

__global__ __launch_bounds__(256) void rank_kernel(
    const int* __restrict__ ei, int* __restrict__ cnt, unsigned short* __restrict__ tmp)
{
    int e = blockIdx.x * 256 + threadIdx.x;   // grid exact
    int d = ei[EE + e];
    tmp[e] = (unsigned short)atomicAdd(&cnt[d], 1);
}

// ---- two-level parallel scan: cnt[NN] -> off[NN+1] (exclusive) ----
__global__ __launch_bounds__(256) void partial_kernel(
    const int* __restrict__ cnt, int* __restrict__ partials)
{
    int i0 = blockIdx.x * 1024 + threadIdx.x * 4;
    int s = 0;
    if (i0 + 3 < NN) {
        int4 v = *(const int4*)(cnt + i0);
        s = v.x + v.y + v.z + v.w;
    } else {
        for (int i = i0; i < NN; ++i) s += cnt[i];
    }
#pragma unroll
    for (int d = 1; d < 64; d <<= 1) s += __shfl_xor(s, d);
    __shared__ int ws_[4];
    if ((threadIdx.x & 63) == 0) ws_[threadIdx.x >> 6] = s;
    __syncthreads();
    if (threadIdx.x == 0) partials[blockIdx.x] = ws_[0] + ws_[1] + ws_[2] + ws_[3];
}

__global__ __launch_bounds__(128) void scan_partials(
    int* __restrict__ partials, int* __restrict__ off)
{
    __shared__ int ls[128];
    int t = threadIdx.x;
    int v = (t < 98) ? partials[t] : 0;
    ls[t] = v;
    __syncthreads();
#pragma unroll
    for (int d = 1; d < 128; d <<= 1) {
        int u = (t >= d) ? ls[t - d] : 0;
        __syncthreads();
        ls[t] += u;
        __syncthreads();
    }
    if (t < 98) partials[t] = ls[t] - v;   // exclusive block base
    if (t == 127) off[NN] = ls[127];       // total == EE
}

__global__ __launch_bounds__(256) void final_scan(
    const int* __restrict__ cnt, const int* __restrict__ partials, int* __restrict__ off)
{
    int t = threadIdx.x;
    int i0 = blockIdx.x * 1024 + t * 4;
    int4 v = {0, 0, 0, 0};
    if (i0 + 3 < NN) {
        v = *(const int4*)(cnt + i0);
    } else {
        int tv[4] = {0, 0, 0, 0};
        for (int k = 0; k < 4 && i0 + k < NN; ++k) tv[k] = cnt[i0 + k];
        v.x = tv[0]; v.y = tv[1]; v.z = tv[2]; v.w = tv[3];
    }
    int s = v.x + v.y + v.z + v.w;
    __shared__ int ls[256];
    ls[t] = s;
    __syncthreads();
#pragma unroll
    for (int d = 1; d < 256; d <<= 1) {
        int u = (t >= d) ? ls[t - d] : 0;
        __syncthreads();
        ls[t] += u;
        __syncthreads();
    }
    int base = partials[blockIdx.x] + ls[t] - s;
    int4 o;
    o.x = base; o.y = base + v.x; o.z = o.y + v.y; o.w = o.z + v.z;
    if (i0 + 3 < NN) {
        *(int4*)(off + i0) = o;
    } else {
        int oo[4] = {o.x, o.y, o.z, o.w};
        for (int k = 0; k < 4 && i0 + k < NN; ++k) off[i0 + k] = oo[k];
    }
}

__global__ __launch_bounds__(256) void place_kernel(
    const int* __restrict__ ei, const int* __restrict__ off,
    const unsigned short* __restrict__ tmp,
    int* __restrict__ srcs, int* __restrict__ grp)
{
    int e = blockIdx.x * 256 + threadIdx.x;
    int s = ei[e], d = ei[EE + e];
    int p = off[d] + (int)tmp[e];
    srcs[p] = s;
    if ((p & 63) == 0) grp[p >> 6] = d;
}

// One wave = 64 CSR-consecutive edges = two 32-edge M-tiles.
// layer1 (K1-pad-16 MFMA) -> LDS T -> layer2 (2x K16 MFMA) -> LDS T ->
// linear head 32->4 (2x K16 MFMA) -> per-lane run-merge + atomicAdd into agg4.
__global__ __launch_bounds__(256) void edge_mfma(
    const float* __restrict__ feat, int fdim,                     // 4 (enc/x) or 2 (dec/z)
    const float* __restrict__ W1, const float* __restrict__ b1,   // [2*fdim][32]
    const float* __restrict__ W2, const float* __restrict__ b2,   // [32][32]
    const float* __restrict__ hA, const float* __restrict__ hB, int hmode,
    const int* __restrict__ srcs, const int* __restrict__ off, const int* __restrict__ grp,
    float* __restrict__ agg4)
{
    __shared__ short sm[4][64][68];   // bf16, stride 68 (136B rows, 8B aligned)
    int tid = threadIdx.x;
    int w = tid >> 6, l = tid & 63;
    int j = l & 31, h = l >> 5;
    int gw = blockIdx.x * 4 + w;      // global wave id, < 50000
    int ebase = gw * 64;
    int K1 = 2 * fdim;

    // ---- B fragments (per-lane constants) ----
    bf16x8 bL1, bk0, bk1, hb0, hb1;
#pragma unroll
    for (int i = 0; i < 8; ++i) {
        bL1[i] = (h == 0 && i < K1) ? f2bf(W1[i * 32 + j]) : (short)0;
        int k0 = 8 * h + i, k1 = 16 + 8 * h + i;
        bk0[i] = f2bf(W2[k0 * 32 + j]);
        bk1[i] = f2bf(W2[k1 * 32 + j]);
        short w0 = 0, w1 = 0;
        if (j < 4) {
            if (hmode == 0) {   // enc: hA=muW [32][2], hB=vW [32][2]
                w0 = (j < 2) ? f2bf(hA[k0 * 2 + j]) : f2bf(hB[k0 * 2 + (j - 2)]);
                w1 = (j < 2) ? f2bf(hA[k1 * 2 + j]) : f2bf(hB[k1 * 2 + (j - 2)]);
            } else {            // dec: hA=W3 [32][4]
                w0 = f2bf(hA[k0 * 4 + j]);
                w1 = f2bf(hA[k1 * 4 + j]);
            }
        }
        hb0[i] = w0; hb1[i] = w1;
    }
    float bias1 = b1[j], bias2 = b2[j];

    // ---- input A-fragments: lanes h==0 hold k=0..7 (= [x_i, x_j-x_i]), h==1 zero ----
    bf16x8 aIn0 = {0,0,0,0,0,0,0,0}, aIn1 = {0,0,0,0,0,0,0,0};
    if (h == 0) {
        int e0 = ebase + j, e1 = e0 + 32;
        int n = grp[gw];
        while (off[n + 1] <= e0) ++n;
        int d0 = n;
        while (off[n + 1] <= e1) ++n;
        int d1 = n;
        int s0 = srcs[e0], s1 = srcs[e1];
        if (fdim == 4) {
            float4 xd = *(const float4*)(feat + 4 * d0);
            float4 xs = *(const float4*)(feat + 4 * s0);
            aIn0[0] = f2bf(xd.x); aIn0[1] = f2bf(xd.y);
            aIn0[2] = f2bf(xd.z); aIn0[3] = f2bf(xd.w);
            aIn0[4] = f2bf(xs.x - xd.x); aIn0[5] = f2bf(xs.y - xd.y);
            aIn0[6] = f2bf(xs.z - xd.z); aIn0[7] = f2bf(xs.w - xd.w);
            xd = *(const float4*)(feat + 4 * d1);
            xs = *(const float4*)(feat + 4 * s1);
            aIn1[0] = f2bf(xd.x); aIn1[1] = f2bf(xd.y);
            aIn1[2] = f2bf(xd.z); aIn1[3] = f2bf(xd.w);
            aIn1[4] = f2bf(xs.x - xd.x); aIn1[5] = f2bf(xs.y - xd.y);
            aIn1[6] = f2bf(xs.z - xd.z); aIn1[7] = f2bf(xs.w - xd.w);
        } else {
            float2 zd = *(const float2*)(feat + 2 * d0);
            float2 zs = *(const float2*)(feat + 2 * s0);
            aIn0[0] = f2bf(zd.x); aIn0[1] = f2bf(zd.y);
            aIn0[2] = f2bf(zs.x - zd.x); aIn0[3] = f2bf(zs.y - zd.y);
            zd = *(const float2*)(feat + 2 * d1);
            zs = *(const float2*)(feat + 2 * s1);
            aIn1[0] = f2bf(zd.x); aIn1[1] = f2bf(zd.y);
            aIn1[2] = f2bf(zs.x - zd.x); aIn1[3] = f2bf(zs.y - zd.y);
        }
    }

    f32x16 czero = {0.f,0.f,0.f,0.f,0.f,0.f,0.f,0.f,0.f,0.f,0.f,0.f,0.f,0.f,0.f,0.f};

    // ---- layer 1 ----
    f32x16 p0 = __builtin_amdgcn_mfma_f32_32x32x16_bf16(aIn0, bL1, czero, 0, 0, 0);
    f32x16 p1 = __builtin_amdgcn_mfma_f32_32x32x16_bf16(aIn1, bL1, czero, 0, 0, 0);
#pragma unroll
    for (int r = 0; r < 16; ++r) {
        int row = (r & 3) + 8 * (r >> 2) + 4 * h;
        sm[w][row][j]      = f2bf(fmaxf(p0[r] + bias1, 0.f));
        sm[w][row + 32][j] = f2bf(fmaxf(p1[r] + bias1, 0.f));
    }
    __syncthreads();

    // ---- transpose read: layer-2 A frags ----
    s16x4 q0 = *(const s16x4*)&sm[w][j][8 * h];
    s16x4 q1 = *(const s16x4*)&sm[w][j][8 * h + 4];
    s16x4 q2 = *(const s16x4*)&sm[w][j][16 + 8 * h];
    s16x4 q3 = *(const s16x4*)&sm[w][j][16 + 8 * h + 4];
    s16x4 q4 = *(const s16x4*)&sm[w][32 + j][8 * h];
    s16x4 q5 = *(const s16x4*)&sm[w][32 + j][8 * h + 4];
    s16x4 q6 = *(const s16x4*)&sm[w][32 + j][16 + 8 * h];
    s16x4 q7 = *(const s16x4*)&sm[w][32 + j][16 + 8 * h + 4];
    bf16x8 a0k0 = {q0[0],q0[1],q0[2],q0[3],q1[0],q1[1],q1[2],q1[3]};
    bf16x8 a0k1 = {q2[0],q2[1],q2[2],q2[3],q3[0],q3[1],q3[2],q3[3]};
    bf16x8 a1k0 = {q4[0],q4[1],q4[2],q4[3],q5[0],q5[1],q5[2],q5[3]};
    bf16x8 a1k1 = {q6[0],q6[1],q6[2],q6[3],q7[0],q7[1],q7[2],q7[3]};

    // ---- layer 2 ----
    f32x16 acc0 = czero, acc1 = czero;
    acc0 = __builtin_amdgcn_mfma_f32_32x32x16_bf16(a0k0, bk0, acc0, 0, 0, 0);
    acc0 = __builtin_amdgcn_mfma_f32_32x32x16_bf16(a0k1, bk1, acc0, 0, 0, 0);
    acc1 = __builtin_amdgcn_mfma_f32_32x32x16_bf16(a1k0, bk0, acc1, 0, 0, 0);
    acc1 = __builtin_amdgcn_mfma_f32_32x32x16_bf16(a1k1, bk1, acc1, 0, 0, 0);
    __syncthreads();   // all T1 reads done before overwriting sm

#pragma unroll
    for (int r = 0; r < 16; ++r) {
        int row = (r & 3) + 8 * (r >> 2) + 4 * h;
        sm[w][row][j]      = f2bf(fmaxf(acc0[r] + bias2, 0.f));
        sm[w][row + 32][j] = f2bf(fmaxf(acc1[r] + bias2, 0.f));
    }
    __syncthreads();

    // ---- transpose read: head A frags ----
    q0 = *(const s16x4*)&sm[w][j][8 * h];
    q1 = *(const s16x4*)&sm[w][j][8 * h + 4];
    q2 = *(const s16x4*)&sm[w][j][16 + 8 * h];
    q3 = *(const s16x4*)&sm[w][j][16 + 8 * h + 4];
    q4 = *(const s16x4*)&sm[w][32 + j][8 * h];
    q5 = *(const s16x4*)&sm[w][32 + j][8 * h + 4];
    q6 = *(const s16x4*)&sm[w][32 + j][16 + 8 * h];
    q7 = *(const s16x4*)&sm[w][32 + j][16 + 8 * h + 4];
    bf16x8 m0k0 = {q0[0],q0[1],q0[2],q0[3],q1[0],q1[1],q1[2],q1[3]};
    bf16x8 m0k1 = {q2[0],q2[1],q2[2],q2[3],q3[0],q3[1],q3[2],q3[3]};
    bf16x8 m1k0 = {q4[0],q4[1],q4[2],q4[3],q5[0],q5[1],q5[2],q5[3]};
    bf16x8 m1k1 = {q6[0],q6[1],q6[2],q6[3],q7[0],q7[1],q7[2],q7[3]};

    // ---- head 32->4 (linear; mean applied post-aggregation) ----
    f32x16 hc0 = czero, hc1 = czero;
    hc0 = __builtin_amdgcn_mfma_f32_32x32x16_bf16(m0k0, hb0, hc0, 0, 0, 0);
    hc0 = __builtin_amdgcn_mfma_f32_32x32x16_bf16(m0k1, hb1, hc0, 0, 0, 0);
    hc1 = __builtin_amdgcn_mfma_f32_32x32x16_bf16(m1k0, hb0, hc1, 0, 0, 0);
    hc1 = __builtin_amdgcn_mfma_f32_32x32x16_bf16(m1k1, hb1, hc1, 0, 0, 0);

    // ---- segmented flush: lanes j<4 own channel j; rows ascend with reg ----
    if (j < 4) {
        int n = grp[gw];
        int nend = off[n + 1];
        float acc = 0.f;
#pragma unroll
        for (int r = 0; r < 16; ++r) {
            int e = ebase + (r & 3) + 8 * (r >> 2) + 4 * h;
            while (e >= nend) {
                if (acc != 0.f) { atomicAdd(&agg4[n * 4 + j], acc); acc = 0.f; }
                ++n; nend = off[n + 1];
            }
            acc += hc0[r];
        }
#pragma unroll
        for (int r = 0; r < 16; ++r) {
            int e = ebase + 32 + (r & 3) + 8 * (r >> 2) + 4 * h;
            while (e >= nend) {
                if (acc != 0.f) { atomicAdd(&agg4[n * 4 + j], acc); acc = 0.f; }
                ++n; nend = off[n + 1];
            }
            acc += hc1[r];
        }
        if (acc != 0.f) atomicAdd(&agg4[n * 4 + j], acc);
    }
}

__global__ __launch_bounds__(256) void node_kernel(
    const float* __restrict__ h4, const int* __restrict__ off,
    const float* __restrict__ eps,
    const float* __restrict__ mub, const float* __restrict__ vb,
    float* __restrict__ z, float* __restrict__ out)
{
    int n = blockIdx.x * 256 + threadIdx.x;
    if (n >= NN) return;
    float inv = 1.f / fmaxf((float)(off[n + 1] - off[n]), 1.f);
    float4 a = *(const float4*)(h4 + 4 * n);
    float mu0 = a.x * inv + mub[0], mu1 = a.y * inv + mub[1];
    float lv0 = a.z * inv + vb[0],  lv1 = a.w * inv + vb[1];
    out[4 * NN + 2 * n]     = mu0;
    out[4 * NN + 2 * n + 1] = mu1;
    out[6 * NN + 2 * n]     = lv0;
    out[6 * NN + 2 * n + 1] = lv1;
    float2 zz;
    zz.x = mu0 + eps[2 * n]     * expf(0.5f * lv0);
    zz.y = mu1 + eps[2 * n + 1] * expf(0.5f * lv1);
    *(float2*)(z + 2 * n) = zz;
}

__global__ __launch_bounds__(256) void final_kernel(
    const float* __restrict__ o4, const int* __restrict__ off,
    const float* __restrict__ b3, float* __restrict__ out)
{
    int n = blockIdx.x * 256 + threadIdx.x;
    if (n >= NN) return;
    float inv = 1.f / fmaxf((float)(off[n + 1] - off[n]), 1.f);
    float4 a = *(const float4*)(o4 + 4 * n);
    float4 r;
    r.x = a.x * inv + b3[0]; r.y = a.y * inv + b3[1];
    r.z = a.z * inv + b3[2]; r.w = a.w * inv + b3[3];
    *(float4*)(out + 4 * n) = r;
}

extern "C" void kernel_launch(void* const* d_in, const int* in_sizes, int n_in,
                              void* d_out, int out_size, void* d_ws, size_t ws_size,
                              hipStream_t stream)
{
    const float* x     = (const float*)d_in[0];
    const int*   ei    = (const int*)d_in[1];
    const float* eps   = (const float*)d_in[2];
    const float* encW1 = (const float*)d_in[3];
    const float* encb1 = (const float*)d_in[4];
    const float* encW2 = (const float*)d_in[5];
    const float* encb2 = (const float*)d_in[6];
    const float* muW   = (const float*)d_in[7];
    const float* mub   = (const float*)d_in[8];
    const float* vW    = (const float*)d_in[9];
    const float* vb    = (const float*)d_in[10];
    const float* decW1 = (const float*)d_in[11];
    const float* decb1 = (const float*)d_in[12];
    const float* decW2 = (const float*)d_in[13];
    const float* decb2 = (const float*)d_in[14];
    const float* decW3 = (const float*)d_in[15];
    const float* decb3 = (const float*)d_in[16];

    int*   wsI  = (int*)d_ws;
    float* wsF  = (float*)d_ws;
    int*   srcs = wsI + WS_SRCS;
    unsigned short* tmp = (unsigned short*)(wsI + WS_TMP);
    int*   off  = wsI + WS_OFF;
    int*   cnt  = wsI + WS_CNT;
    int*   grp  = wsI + WS_CNT;       // overlays cnt (dead after scan)
    int*   part = wsI + WS_PART;
    float* h4   = wsF + WS_H4;
    float* out4 = wsF + WS_OUT4;
    float* z    = wsF + WS_Z;

    hipMemsetAsync(wsI + WS_ZERO_BEGIN, 0, (size_t)WS_ZERO_COUNT * 4, stream);

    dim3 blk(256);
    dim3 egrid(12500);
    dim3 ngrid((NN + 255) / 256);
    dim3 sgrid(98);

    rank_kernel<<<egrid, blk, 0, stream>>>(ei, cnt, tmp);
    partial_kernel<<<sgrid, blk, 0, stream>>>(cnt, part);
    scan_partials<<<dim3(1), dim3(128), 0, stream>>>(part, off);
    final_scan<<<sgrid, blk, 0, stream>>>(cnt, part, off);
    place_kernel<<<egrid, blk, 0, stream>>>(ei, off, tmp, srcs, grp);
    edge_mfma<<<egrid, blk, 0, stream>>>(x, 4, encW1, encb1, encW2, encb2,
                                         muW, vW, 0, srcs, off, grp, h4);
    node_kernel<<<ngrid, blk, 0, stream>>>(h4, off, eps, mub, vb, z, (float*)d_out);
    edge_mfma<<<egrid, blk, 0, stream>>>(z, 2, decW1, decb1, decW2, decb2,
                                         decW3, decW3, 1, srcs, off, grp, out4);
    final_kernel<<<ngrid, blk, 0, stream>>>(out4, off, decb3, (float*)d_out);
}

// Round 6
// 381.160 us; speedup vs baseline: 15.8058x; 1.1817x over previous
//
#include <hip/hip_runtime.h>
#include <hip/hip_bf16.h>

#define NN 100000
#define EE 3200000

typedef short bf16x8 __attribute__((ext_vector_type(8)));
typedef short s16x4  __attribute__((ext_vector_type(4)));
typedef float f32x16 __attribute__((ext_vector_type(16)));

// ws layout (4-byte units), ~30.4 MB:
#define WS_SD2  0            // int2[EE] = 6.4M ints (src,dst per CSR slot)
#define WS_OFF  6400000      // int[NN+1], pad to 6500032
#define WS_CNT  6500032      // int[NN]
#define WS_PART 6600032      // int[128]
#define WS_H4   6600192      // float[NN*4]  -- tmp u8[EE] overlays h4+out4 (dead before memset2)
#define WS_OUT4 7000192      // float[NN*4]
#define WS_Z    7400192      // float[NN*2]
#define WS_TMP  6600192      // u8[EE] overlay of [WS_H4, WS_H4+800000)

static __device__ __forceinline__ short f2bf(float f) {
    __hip_bfloat16 b = __float2bfloat16(f);
    return __builtin_bit_cast(short, b);
}

__global__ __launch_bounds__(256) void rank_kernel(
    const int* __restrict__ ei, int* __restrict__ cnt, unsigned char* __restrict__ tmp)
{
    int e = blockIdx.x * 256 + threadIdx.x;   // grid exact
    int d = ei[EE + e];
    tmp[e] = (unsigned char)atomicAdd(&cnt[d], 1);
}

// ---- two-level parallel scan: cnt[NN] -> off[NN+1] (exclusive) ----
__global__ __launch_bounds__(256) void partial_kernel(
    const int* __restrict__ cnt, int* __restrict__ partials)
{
    int i0 = blockIdx.x * 1024 + threadIdx.x * 4;
    int s = 0;
    if (i0 + 3 < NN) {
        int4 v = *(const int4*)(cnt + i0);
        s = v.x + v.y + v.z + v.w;
    } else {
        for (int i = i0; i < NN; ++i) s += cnt[i];
    }
#pragma unroll
    for (int d = 1; d < 64; d <<= 1) s += __shfl_xor(s, d);
    __shared__ int ws_[4];
    if ((threadIdx.x & 63) == 0) ws_[threadIdx.x >> 6] = s;
    __syncthreads();
    if (threadIdx.x == 0) partials[blockIdx.x] = ws_[0] + ws_[1] + ws_[2] + ws_[3];
}

__global__ __launch_bounds__(128) void scan_partials(
    int* __restrict__ partials, int* __restrict__ off)
{
    __shared__ int ls[128];
    int t = threadIdx.x;
    int v = (t < 98) ? partials[t] : 0;
    ls[t] = v;
    __syncthreads();
#pragma unroll
    for (int d = 1; d < 128; d <<= 1) {
        int u = (t >= d) ? ls[t - d] : 0;
        __syncthreads();
        ls[t] += u;
        __syncthreads();
    }
    if (t < 98) partials[t] = ls[t] - v;   // exclusive block base
    if (t == 127) off[NN] = ls[127];       // total == EE
}

__global__ __launch_bounds__(256) void final_scan(
    const int* __restrict__ cnt, const int* __restrict__ partials, int* __restrict__ off)
{
    int t = threadIdx.x;
    int i0 = blockIdx.x * 1024 + t * 4;
    int4 v = {0, 0, 0, 0};
    if (i0 + 3 < NN) {
        v = *(const int4*)(cnt + i0);
    } else {
        int tv[4] = {0, 0, 0, 0};
        for (int k = 0; k < 4 && i0 + k < NN; ++k) tv[k] = cnt[i0 + k];
        v.x = tv[0]; v.y = tv[1]; v.z = tv[2]; v.w = tv[3];
    }
    int s = v.x + v.y + v.z + v.w;
    __shared__ int ls[256];
    ls[t] = s;
    __syncthreads();
#pragma unroll
    for (int d = 1; d < 256; d <<= 1) {
        int u = (t >= d) ? ls[t - d] : 0;
        __syncthreads();
        ls[t] += u;
        __syncthreads();
    }
    int base = partials[blockIdx.x] + ls[t] - s;
    int4 o;
    o.x = base; o.y = base + v.x; o.z = o.y + v.y; o.w = o.z + v.z;
    if (i0 + 3 < NN) {
        *(int4*)(off + i0) = o;
    } else {
        int oo[4] = {o.x, o.y, o.z, o.w};
        for (int k = 0; k < 4 && i0 + k < NN; ++k) off[i0 + k] = oo[k];
    }
}

__global__ __launch_bounds__(256) void place_kernel(
    const int* __restrict__ ei, const int* __restrict__ off,
    const unsigned char* __restrict__ tmp, int2* __restrict__ sd2)
{
    int e = blockIdx.x * 256 + threadIdx.x;
    int s = ei[e], d = ei[EE + e];
    int p = off[d] + (int)tmp[e];
    sd2[p] = make_int2(s, d);
}

// One wave per block; 64 CSR-consecutive edges = two 32-edge M-tiles.
// layer1 (K1-pad-16 MFMA) -> LDS T -> layer2 (2x K16 MFMA) -> LDS T ->
// linear head 32->4 (2x K16 MFMA) -> per-lane run-merge (dst from LDS) + atomicAdd.
__global__ __launch_bounds__(64) void edge_mfma(
    const float* __restrict__ feat, int fdim,                     // 4 (enc/x) or 2 (dec/z)
    const float* __restrict__ W1, const float* __restrict__ b1,   // [2*fdim][32]
    const float* __restrict__ W2, const float* __restrict__ b2,   // [32][32]
    const float* __restrict__ hA, const float* __restrict__ hB, int hmode,
    const int2* __restrict__ sd2,
    float* __restrict__ agg4)
{
    __shared__ short sm[64][68];   // bf16, stride 68 (136B rows)
    __shared__ int   sd[64];
    int l = threadIdx.x;
    int j = l & 31, h = l >> 5;
    int ebase = blockIdx.x * 64;
    int K1 = 2 * fdim;

    // ---- per-lane (src,dst); stage dst in LDS for the flush ----
    int2 me = sd2[ebase + l];
    sd[l] = me.y;
    int s1 = __shfl(me.x, 32 + j);
    int d1 = __shfl(me.y, 32 + j);

    // ---- B fragments (per-lane constants) ----
    bf16x8 bL1, bk0, bk1, hb0, hb1;
#pragma unroll
    for (int i = 0; i < 8; ++i) {
        bL1[i] = (h == 0 && i < K1) ? f2bf(W1[i * 32 + j]) : (short)0;
        int k0 = 8 * h + i, k1 = 16 + 8 * h + i;
        bk0[i] = f2bf(W2[k0 * 32 + j]);
        bk1[i] = f2bf(W2[k1 * 32 + j]);
        short w0 = 0, w1 = 0;
        if (j < 4) {
            if (hmode == 0) {   // enc: hA=muW [32][2], hB=vW [32][2]
                w0 = (j < 2) ? f2bf(hA[k0 * 2 + j]) : f2bf(hB[k0 * 2 + (j - 2)]);
                w1 = (j < 2) ? f2bf(hA[k1 * 2 + j]) : f2bf(hB[k1 * 2 + (j - 2)]);
            } else {            // dec: hA=W3 [32][4]
                w0 = f2bf(hA[k0 * 4 + j]);
                w1 = f2bf(hA[k1 * 4 + j]);
            }
        }
        hb0[i] = w0; hb1[i] = w1;
    }
    float bias1 = b1[j], bias2 = b2[j];

    // ---- input A-fragments: lanes h==0 hold k=0..K1-1 = [x_i, x_j-x_i] ----
    bf16x8 aIn0 = {0,0,0,0,0,0,0,0}, aIn1 = {0,0,0,0,0,0,0,0};
    if (h == 0) {
        int s0 = me.x, d0 = me.y;
        if (fdim == 4) {
            float4 xd = *(const float4*)(feat + 4 * d0);
            float4 xs = *(const float4*)(feat + 4 * s0);
            aIn0[0] = f2bf(xd.x); aIn0[1] = f2bf(xd.y);
            aIn0[2] = f2bf(xd.z); aIn0[3] = f2bf(xd.w);
            aIn0[4] = f2bf(xs.x - xd.x); aIn0[5] = f2bf(xs.y - xd.y);
            aIn0[6] = f2bf(xs.z - xd.z); aIn0[7] = f2bf(xs.w - xd.w);
            xd = *(const float4*)(feat + 4 * d1);
            xs = *(const float4*)(feat + 4 * s1);
            aIn1[0] = f2bf(xd.x); aIn1[1] = f2bf(xd.y);
            aIn1[2] = f2bf(xd.z); aIn1[3] = f2bf(xd.w);
            aIn1[4] = f2bf(xs.x - xd.x); aIn1[5] = f2bf(xs.y - xd.y);
            aIn1[6] = f2bf(xs.z - xd.z); aIn1[7] = f2bf(xs.w - xd.w);
        } else {
            float2 zd = *(const float2*)(feat + 2 * d0);
            float2 zs = *(const float2*)(feat + 2 * s0);
            aIn0[0] = f2bf(zd.x); aIn0[1] = f2bf(zd.y);
            aIn0[2] = f2bf(zs.x - zd.x); aIn0[3] = f2bf(zs.y - zd.y);
            zd = *(const float2*)(feat + 2 * d1);
            zs = *(const float2*)(feat + 2 * s1);
            aIn1[0] = f2bf(zd.x); aIn1[1] = f2bf(zd.y);
            aIn1[2] = f2bf(zs.x - zd.x); aIn1[3] = f2bf(zs.y - zd.y);
        }
    }

    f32x16 czero = {0.f,0.f,0.f,0.f,0.f,0.f,0.f,0.f,0.f,0.f,0.f,0.f,0.f,0.f,0.f,0.f};

    // ---- layer 1 ----
    f32x16 p0 = __builtin_amdgcn_mfma_f32_32x32x16_bf16(aIn0, bL1, czero, 0, 0, 0);
    f32x16 p1 = __builtin_amdgcn_mfma_f32_32x32x16_bf16(aIn1, bL1, czero, 0, 0, 0);
#pragma unroll
    for (int r = 0; r < 16; ++r) {
        int row = (r & 3) + 8 * (r >> 2) + 4 * h;
        sm[row][j]      = f2bf(fmaxf(p0[r] + bias1, 0.f));
        sm[row + 32][j] = f2bf(fmaxf(p1[r] + bias1, 0.f));
    }
    __syncthreads();

    // ---- transpose read: layer-2 A frags ----
    s16x4 q0 = *(const s16x4*)&sm[j][8 * h];
    s16x4 q1 = *(const s16x4*)&sm[j][8 * h + 4];
    s16x4 q2 = *(const s16x4*)&sm[j][16 + 8 * h];
    s16x4 q3 = *(const s16x4*)&sm[j][16 + 8 * h + 4];
    s16x4 q4 = *(const s16x4*)&sm[32 + j][8 * h];
    s16x4 q5 = *(const s16x4*)&sm[32 + j][8 * h + 4];
    s16x4 q6 = *(const s16x4*)&sm[32 + j][16 + 8 * h];
    s16x4 q7 = *(const s16x4*)&sm[32 + j][16 + 8 * h + 4];
    bf16x8 a0k0 = {q0[0],q0[1],q0[2],q0[3],q1[0],q1[1],q1[2],q1[3]};
    bf16x8 a0k1 = {q2[0],q2[1],q2[2],q2[3],q3[0],q3[1],q3[2],q3[3]};
    bf16x8 a1k0 = {q4[0],q4[1],q4[2],q4[3],q5[0],q5[1],q5[2],q5[3]};
    bf16x8 a1k1 = {q6[0],q6[1],q6[2],q6[3],q7[0],q7[1],q7[2],q7[3]};

    // ---- layer 2 ----
    f32x16 acc0 = czero, acc1 = czero;
    acc0 = __builtin_amdgcn_mfma_f32_32x32x16_bf16(a0k0, bk0, acc0, 0, 0, 0);
    acc0 = __builtin_amdgcn_mfma_f32_32x32x16_bf16(a0k1, bk1, acc0, 0, 0, 0);
    acc1 = __builtin_amdgcn_mfma_f32_32x32x16_bf16(a1k0, bk0, acc1, 0, 0, 0);
    acc1 = __builtin_amdgcn_mfma_f32_32x32x16_bf16(a1k1, bk1, acc1, 0, 0, 0);
    __syncthreads();   // all T1 reads done before overwriting sm

#pragma unroll
    for (int r = 0; r < 16; ++r) {
        int row = (r & 3) + 8 * (r >> 2) + 4 * h;
        sm[row][j]      = f2bf(fmaxf(acc0[r] + bias2, 0.f));
        sm[row + 32][j] = f2bf(fmaxf(acc1[r] + bias2, 0.f));
    }
    __syncthreads();

    // ---- transpose read: head A frags ----
    q0 = *(const s16x4*)&sm[j][8 * h];
    q1 = *(const s16x4*)&sm[j][8 * h + 4];
    q2 = *(const s16x4*)&sm[j][16 + 8 * h];
    q3 = *(const s16x4*)&sm[j][16 + 8 * h + 4];
    q4 = *(const s16x4*)&sm[32 + j][8 * h];
    q5 = *(const s16x4*)&sm[32 + j][8 * h + 4];
    q6 = *(const s16x4*)&sm[32 + j][16 + 8 * h];
    q7 = *(const s16x4*)&sm[32 + j][16 + 8 * h + 4];
    bf16x8 m0k0 = {q0[0],q0[1],q0[2],q0[3],q1[0],q1[1],q1[2],q1[3]};
    bf16x8 m0k1 = {q2[0],q2[1],q2[2],q2[3],q3[0],q3[1],q3[2],q3[3]};
    bf16x8 m1k0 = {q4[0],q4[1],q4[2],q4[3],q5[0],q5[1],q5[2],q5[3]};
    bf16x8 m1k1 = {q6[0],q6[1],q6[2],q6[3],q7[0],q7[1],q7[2],q7[3]};

    // ---- head 32->4 (linear; mean applied post-aggregation) ----
    f32x16 hc0 = czero, hc1 = czero;
    hc0 = __builtin_amdgcn_mfma_f32_32x32x16_bf16(m0k0, hb0, hc0, 0, 0, 0);
    hc0 = __builtin_amdgcn_mfma_f32_32x32x16_bf16(m0k1, hb1, hc0, 0, 0, 0);
    hc1 = __builtin_amdgcn_mfma_f32_32x32x16_bf16(m1k0, hb0, hc1, 0, 0, 0);
    hc1 = __builtin_amdgcn_mfma_f32_32x32x16_bf16(m1k1, hb1, hc1, 0, 0, 0);

    // ---- segmented flush: lanes j<4 own channel j; dst from LDS (no off loads) ----
    if (j < 4) {
        int cur = sd[4 * h];
        float acc = 0.f;
#pragma unroll
        for (int r = 0; r < 16; ++r) {
            int row = (r & 3) + 8 * (r >> 2) + 4 * h;
            int dr = sd[row];
            if (dr != cur) { atomicAdd(&agg4[cur * 4 + j], acc); acc = 0.f; cur = dr; }
            acc += hc0[r];
        }
#pragma unroll
        for (int r = 0; r < 16; ++r) {
            int row = 32 + (r & 3) + 8 * (r >> 2) + 4 * h;
            int dr = sd[row];
            if (dr != cur) { atomicAdd(&agg4[cur * 4 + j], acc); acc = 0.f; cur = dr; }
            acc += hc1[r];
        }
        atomicAdd(&agg4[cur * 4 + j], acc);
    }
}

__global__ __launch_bounds__(256) void node_kernel(
    const float* __restrict__ h4, const int* __restrict__ off,
    const float* __restrict__ eps,
    const float* __restrict__ mub, const float* __restrict__ vb,
    float* __restrict__ z, float* __restrict__ out)
{
    int n = blockIdx.x * 256 + threadIdx.x;
    if (n >= NN) return;
    float inv = 1.f / fmaxf((float)(off[n + 1] - off[n]), 1.f);
    float4 a = *(const float4*)(h4 + 4 * n);
    float mu0 = a.x * inv + mub[0], mu1 = a.y * inv + mub[1];
    float lv0 = a.z * inv + vb[0],  lv1 = a.w * inv + vb[1];
    out[4 * NN + 2 * n]     = mu0;
    out[4 * NN + 2 * n + 1] = mu1;
    out[6 * NN + 2 * n]     = lv0;
    out[6 * NN + 2 * n + 1] = lv1;
    float2 zz;
    zz.x = mu0 + eps[2 * n]     * expf(0.5f * lv0);
    zz.y = mu1 + eps[2 * n + 1] * expf(0.5f * lv1);
    *(float2*)(z + 2 * n) = zz;
}

__global__ __launch_bounds__(256) void final_kernel(
    const float* __restrict__ o4, const int* __restrict__ off,
    const float* __restrict__ b3, float* __restrict__ out)
{
    int n = blockIdx.x * 256 + threadIdx.x;
    if (n >= NN) return;
    float inv = 1.f / fmaxf((float)(off[n + 1] - off[n]), 1.f);
    float4 a = *(const float4*)(o4 + 4 * n);
    float4 r;
    r.x = a.x * inv + b3[0]; r.y = a.y * inv + b3[1];
    r.z = a.z * inv + b3[2]; r.w = a.w * inv + b3[3];
    *(float4*)(out + 4 * n) = r;
}

extern "C" void kernel_launch(void* const* d_in, const int* in_sizes, int n_in,
                              void* d_out, int out_size, void* d_ws, size_t ws_size,
                              hipStream_t stream)
{
    const float* x     = (const float*)d_in[0];
    const int*   ei    = (const int*)d_in[1];
    const float* eps   = (const float*)d_in[2];
    const float* encW1 = (const float*)d_in[3];
    const float* encb1 = (const float*)d_in[4];
    const float* encW2 = (const float*)d_in[5];
    const float* encb2 = (const float*)d_in[6];
    const float* muW   = (const float*)d_in[7];
    const float* mub   = (const float*)d_in[8];
    const float* vW    = (const float*)d_in[9];
    const float* vb    = (const float*)d_in[10];
    const float* decW1 = (const float*)d_in[11];
    const float* decb1 = (const float*)d_in[12];
    const float* decW2 = (const float*)d_in[13];
    const float* decb2 = (const float*)d_in[14];
    const float* decW3 = (const float*)d_in[15];
    const float* decb3 = (const float*)d_in[16];

    int*   wsI  = (int*)d_ws;
    float* wsF  = (float*)d_ws;
    int2*  sd2  = (int2*)(wsI + WS_SD2);
    int*   off  = wsI + WS_OFF;
    int*   cnt  = wsI + WS_CNT;
    int*   part = wsI + WS_PART;
    unsigned char* tmp = (unsigned char*)(wsI + WS_TMP);
    float* h4   = wsF + WS_H4;
    float* out4 = wsF + WS_OUT4;
    float* z    = wsF + WS_Z;

    // zero cnt (for rank); h4/out4 zeroed after place (tmp overlays them)
    hipMemsetAsync(wsI + WS_CNT, 0, (size_t)NN * 4, stream);

    dim3 blk(256);
    dim3 egrid(12500);
    dim3 wgrid(50000);               // 64-thread blocks, one wave each
    dim3 ngrid((NN + 255) / 256);
    dim3 sgrid(98);

    rank_kernel<<<egrid, blk, 0, stream>>>(ei, cnt, tmp);
    partial_kernel<<<sgrid, blk, 0, stream>>>(cnt, part);
    scan_partials<<<dim3(1), dim3(128), 0, stream>>>(part, off);
    final_scan<<<sgrid, blk, 0, stream>>>(cnt, part, off);
    place_kernel<<<egrid, blk, 0, stream>>>(ei, off, tmp, sd2);
    // tmp dead from here; zero the accumulators that overlay it
    hipMemsetAsync(wsI + WS_H4, 0, (size_t)800000 * 4, stream);
    edge_mfma<<<wgrid, dim3(64), 0, stream>>>(x, 4, encW1, encb1, encW2, encb2,
                                              muW, vW, 0, sd2, h4);
    node_kernel<<<ngrid, blk, 0, stream>>>(h4, off, eps, mub, vb, z, (float*)d_out);
    edge_mfma<<<wgrid, dim3(64), 0, stream>>>(z, 2, decW1, decb1, decW2, decb2,
                                              decW3, decW3, 1, sd2, out4);
    final_kernel<<<ngrid, blk, 0, stream>>>(out4, off, decb3, (float*)d_out);
}

// Round 8
// 275.472 us; speedup vs baseline: 21.8699x; 1.3837x over previous
//
#include <hip/hip_runtime.h>
#include <hip/hip_bf16.h>

#define NN 100000
#define EE 3200000

#define NBKT 196       // coarse buckets: d>>9, 196*512 >= NN
#define NBH  782       // bhist/bscatter blocks: 782*4096 >= EE
#define NTOT (NBKT*NBH)   // 153272
#define NSB  75        // scan blocks: 75*2048 >= NTOT

typedef short bf16x8 __attribute__((ext_vector_type(8)));
typedef short s16x4  __attribute__((ext_vector_type(4)));
typedef float f32x16 __attribute__((ext_vector_type(16)));

// ---- fast-path ws layout (ints), ~56.2 MB ----
#define WS_SD2F  0            // int2[EE]
#define WS_TMP2  6400000      // int2[EE]
#define WS_OFFF  12800000     // int[NN+1]
#define WS_H     12900032     // int[NTOT]
#define WS_PARTF 13053440     // int[128]
#define WS_H4F   13053568     // float[4N]
#define WS_OUT4F 13453568     // float[4N]
#define WS_ZF    13853568     // float[2N]
#define NEED_FAST ((size_t)14053568 * 4)

// ---- fallback (round-6) ws layout (ints), ~30.4 MB ----
#define FB_SD2  0
#define FB_OFF  6400000
#define FB_CNT  6500032
#define FB_PART 6600032
#define FB_H4   6600192
#define FB_OUT4 7000192
#define FB_Z    7400192
#define FB_TMP  6600192      // u8[EE] overlay of h4/out4

static __device__ __forceinline__ short f2bf(float f) {
    __hip_bfloat16 b = __float2bfloat16(f);
    return __builtin_bit_cast(short, b);
}

// ================= fast-path CSR build (no global atomics) =================

__global__ __launch_bounds__(256) void bhist(
    const int* __restrict__ ei, int* __restrict__ H)
{
    __shared__ int hist[NBKT];
    int t = threadIdx.x;
    if (t < NBKT) hist[t] = 0;
    __syncthreads();
    int base = blockIdx.x * 4096;
#pragma unroll
    for (int k = 0; k < 16; ++k) {
        int e = base + k * 256 + t;
        if (e < EE) atomicAdd(&hist[ei[EE + e] >> 9], 1);
    }
    __syncthreads();
    if (t < NBKT) H[t * NBH + blockIdx.x] = hist[t];
}

// generic two-level exclusive scan (in place), n <= 256*2048
__global__ __launch_bounds__(256) void spart(
    const int* __restrict__ H, int n, int* __restrict__ part)
{
    int t = threadIdx.x;
    int base = blockIdx.x * 2048 + t * 8;
    int s = 0;
#pragma unroll
    for (int k = 0; k < 8; ++k) { int i = base + k; if (i < n) s += H[i]; }
    __shared__ int red[256];
    red[t] = s;
    __syncthreads();
    for (int d = 128; d > 0; d >>= 1) {
        if (t < d) red[t] += red[t + d];
        __syncthreads();
    }
    if (t == 0) part[blockIdx.x] = red[0];
}

__global__ __launch_bounds__(256) void spscan(int* __restrict__ part, int np)
{
    __shared__ int sa[256], sbuf[256];
    int t = threadIdx.x;
    int v = (t < np) ? part[t] : 0;
    int *pa = sa, *pb = sbuf;
    pa[t] = v;
    __syncthreads();
    for (int d = 1; d < 256; d <<= 1) {
        pb[t] = pa[t] + ((t >= d) ? pa[t - d] : 0);
        __syncthreads();
        int* tp = pa; pa = pb; pb = tp;
    }
    if (t < np) part[t] = pa[t] - v;   // exclusive
}

__global__ __launch_bounds__(256) void sfinal(
    int* __restrict__ H, int n, const int* __restrict__ part)
{
    int t = threadIdx.x;
    int base = blockIdx.x * 2048 + t * 8;
    int v[8]; int s = 0;
#pragma unroll
    for (int k = 0; k < 8; ++k) { int i = base + k; v[k] = (i < n) ? H[i] : 0; s += v[k]; }
    __shared__ int sa[256], sbuf[256];
    int *pa = sa, *pb = sbuf;
    pa[t] = s;
    __syncthreads();
    for (int d = 1; d < 256; d <<= 1) {
        pb[t] = pa[t] + ((t >= d) ? pa[t - d] : 0);
        __syncthreads();
        int* tp = pa; pa = pb; pb = tp;
    }
    int run = part[blockIdx.x] + pa[t] - s;
#pragma unroll
    for (int k = 0; k < 8; ++k) { int i = base + k; if (i < n) { H[i] = run; run += v[k]; } }
}

__global__ __launch_bounds__(256) void bscatter(
    const int* __restrict__ ei, const int* __restrict__ S, int2* __restrict__ tmp2)
{
    __shared__ int cur[NBKT];
    int t = threadIdx.x;
    if (t < NBKT) cur[t] = S[t * NBH + blockIdx.x];
    __syncthreads();
    int base = blockIdx.x * 4096;
#pragma unroll
    for (int k = 0; k < 16; ++k) {
        int e = base + k * 256 + t;
        if (e < EE) {
            int s = ei[e], d = ei[EE + e];
            int p = atomicAdd(&cur[d >> 9], 1);
            tmp2[p] = make_int2(s, d);
        }
    }
}

__global__ __launch_bounds__(1024) void bsort(
    const int2* __restrict__ tmp2, const int* __restrict__ S,
    int2* __restrict__ sd2, int* __restrict__ off)
{
    int b = blockIdx.x, t = threadIdx.x;
    int bstart = S[b * NBH];
    int bend = (b < NBKT - 1) ? S[(b + 1) * NBH] : EE;
    __shared__ int hist[512], sa[512], sbuf[512];
    if (t < 512) hist[t] = 0;
    __syncthreads();
    for (int e = bstart + t; e < bend; e += 1024)
        atomicAdd(&hist[tmp2[e].y & 511], 1);
    __syncthreads();
    int v = 0;
    if (t < 512) { v = hist[t]; sa[t] = v; }
    __syncthreads();
    int *pa = sa, *pb = sbuf;
    for (int d = 1; d < 512; d <<= 1) {
        if (t < 512) pb[t] = pa[t] + ((t >= d) ? pa[t - d] : 0);
        __syncthreads();
        int* tp = pa; pa = pb; pb = tp;
    }
    if (t < 512) {
        int base = bstart + pa[t] - v;   // exclusive
        int n = b * 512 + t;
        if (n < NN) off[n] = base;
        hist[t] = base;                  // cursor
    }
    if (b == 0 && t == 0) off[NN] = EE;
    __syncthreads();
    for (int e = bstart + t; e < bend; e += 1024) {
        int2 ed = tmp2[e];
        int p = atomicAdd(&hist[ed.y & 511], 1);
        sd2[p] = ed;
    }
}

// ================= fallback CSR build (round-6, proven) =================

__global__ __launch_bounds__(256) void rank_kernel(
    const int* __restrict__ ei, int* __restrict__ cnt, unsigned char* __restrict__ tmp)
{
    int e = blockIdx.x * 256 + threadIdx.x;
    int d = ei[EE + e];
    tmp[e] = (unsigned char)atomicAdd(&cnt[d], 1);
}

__global__ __launch_bounds__(256) void partial_kernel(
    const int* __restrict__ cnt, int* __restrict__ partials)
{
    int i0 = blockIdx.x * 1024 + threadIdx.x * 4;
    int s = 0;
    if (i0 + 3 < NN) {
        int4 v = *(const int4*)(cnt + i0);
        s = v.x + v.y + v.z + v.w;
    } else {
        for (int i = i0; i < NN; ++i) s += cnt[i];
    }
#pragma unroll
    for (int d = 1; d < 64; d <<= 1) s += __shfl_xor(s, d);
    __shared__ int ws_[4];
    if ((threadIdx.x & 63) == 0) ws_[threadIdx.x >> 6] = s;
    __syncthreads();
    if (threadIdx.x == 0) partials[blockIdx.x] = ws_[0] + ws_[1] + ws_[2] + ws_[3];
}

__global__ __launch_bounds__(128) void scan_partials(
    int* __restrict__ partials, int* __restrict__ off)
{
    __shared__ int ls[128];
    int t = threadIdx.x;
    int v = (t < 98) ? partials[t] : 0;
    ls[t] = v;
    __syncthreads();
#pragma unroll
    for (int d = 1; d < 128; d <<= 1) {
        int u = (t >= d) ? ls[t - d] : 0;
        __syncthreads();
        ls[t] += u;
        __syncthreads();
    }
    if (t < 98) partials[t] = ls[t] - v;
    if (t == 127) off[NN] = ls[127];
}

__global__ __launch_bounds__(256) void final_scan(
    const int* __restrict__ cnt, const int* __restrict__ partials, int* __restrict__ off)
{
    int t = threadIdx.x;
    int i0 = blockIdx.x * 1024 + t * 4;
    int4 v = {0, 0, 0, 0};
    if (i0 + 3 < NN) {
        v = *(const int4*)(cnt + i0);
    } else {
        int tv[4] = {0, 0, 0, 0};
        for (int k = 0; k < 4 && i0 + k < NN; ++k) tv[k] = cnt[i0 + k];
        v.x = tv[0]; v.y = tv[1]; v.z = tv[2]; v.w = tv[3];
    }
    int s = v.x + v.y + v.z + v.w;
    __shared__ int ls[256];
    ls[t] = s;
    __syncthreads();
#pragma unroll
    for (int d = 1; d < 256; d <<= 1) {
        int u = (t >= d) ? ls[t - d] : 0;
        __syncthreads();
        ls[t] += u;
        __syncthreads();
    }
    int base = partials[blockIdx.x] + ls[t] - s;
    int4 o;
    o.x = base; o.y = base + v.x; o.z = o.y + v.y; o.w = o.z + v.z;
    if (i0 + 3 < NN) {
        *(int4*)(off + i0) = o;
    } else {
        int oo[4] = {o.x, o.y, o.z, o.w};
        for (int k = 0; k < 4 && i0 + k < NN; ++k) off[i0 + k] = oo[k];
    }
}

__global__ __launch_bounds__(256) void place_kernel(
    const int* __restrict__ ei, const int* __restrict__ off,
    const unsigned char* __restrict__ tmp, int2* __restrict__ sd2)
{
    int e = blockIdx.x * 256 + threadIdx.x;
    int s = ei[e], d = ei[EE + e];
    int p = off[d] + (int)tmp[e];
    sd2[p] = make_int2(s, d);
}

// ================= shared compute kernels =================

// One wave per block; 64 CSR-consecutive edges = two 32-edge M-tiles.
__global__ __launch_bounds__(64) void edge_mfma(
    const float* __restrict__ feat, int fdim,
    const float* __restrict__ W1, const float* __restrict__ b1,
    const float* __restrict__ W2, const float* __restrict__ b2,
    const float* __restrict__ hA, const float* __restrict__ hB, int hmode,
    const int2* __restrict__ sd2,
    float* __restrict__ agg4)
{
    __shared__ short sm[64][68];
    __shared__ int   sd[64];
    int l = threadIdx.x;
    int j = l & 31, h = l >> 5;
    int ebase = blockIdx.x * 64;
    int K1 = 2 * fdim;

    int2 me = sd2[ebase + l];
    sd[l] = me.y;
    int s1 = __shfl(me.x, 32 + j);
    int d1 = __shfl(me.y, 32 + j);

    bf16x8 bL1, bk0, bk1, hb0, hb1;
#pragma unroll
    for (int i = 0; i < 8; ++i) {
        bL1[i] = (h == 0 && i < K1) ? f2bf(W1[i * 32 + j]) : (short)0;
        int k0 = 8 * h + i, k1 = 16 + 8 * h + i;
        bk0[i] = f2bf(W2[k0 * 32 + j]);
        bk1[i] = f2bf(W2[k1 * 32 + j]);
        short w0 = 0, w1 = 0;
        if (j < 4) {
            if (hmode == 0) {
                w0 = (j < 2) ? f2bf(hA[k0 * 2 + j]) : f2bf(hB[k0 * 2 + (j - 2)]);
                w1 = (j < 2) ? f2bf(hA[k1 * 2 + j]) : f2bf(hB[k1 * 2 + (j - 2)]);
            } else {
                w0 = f2bf(hA[k0 * 4 + j]);
                w1 = f2bf(hA[k1 * 4 + j]);
            }
        }
        hb0[i] = w0; hb1[i] = w1;
    }
    float bias1 = b1[j], bias2 = b2[j];

    bf16x8 aIn0 = {0,0,0,0,0,0,0,0}, aIn1 = {0,0,0,0,0,0,0,0};
    if (h == 0) {
        int s0 = me.x, d0 = me.y;
        if (fdim == 4) {
            float4 xd = *(const float4*)(feat + 4 * d0);
            float4 xs = *(const float4*)(feat + 4 * s0);
            aIn0[0] = f2bf(xd.x); aIn0[1] = f2bf(xd.y);
            aIn0[2] = f2bf(xd.z); aIn0[3] = f2bf(xd.w);
            aIn0[4] = f2bf(xs.x - xd.x); aIn0[5] = f2bf(xs.y - xd.y);
            aIn0[6] = f2bf(xs.z - xd.z); aIn0[7] = f2bf(xs.w - xd.w);
            xd = *(const float4*)(feat + 4 * d1);
            xs = *(const float4*)(feat + 4 * s1);
            aIn1[0] = f2bf(xd.x); aIn1[1] = f2bf(xd.y);
            aIn1[2] = f2bf(xd.z); aIn1[3] = f2bf(xd.w);
            aIn1[4] = f2bf(xs.x - xd.x); aIn1[5] = f2bf(xs.y - xd.y);
            aIn1[6] = f2bf(xs.z - xd.z); aIn1[7] = f2bf(xs.w - xd.w);
        } else {
            float2 zd = *(const float2*)(feat + 2 * d0);
            float2 zs = *(const float2*)(feat + 2 * s0);
            aIn0[0] = f2bf(zd.x); aIn0[1] = f2bf(zd.y);
            aIn0[2] = f2bf(zs.x - zd.x); aIn0[3] = f2bf(zs.y - zd.y);
            zd = *(const float2*)(feat + 2 * d1);
            zs = *(const float2*)(feat + 2 * s1);
            aIn1[0] = f2bf(zd.x); aIn1[1] = f2bf(zd.y);
            aIn1[2] = f2bf(zs.x - zd.x); aIn1[3] = f2bf(zs.y - zd.y);
        }
    }

    f32x16 czero = {0.f,0.f,0.f,0.f,0.f,0.f,0.f,0.f,0.f,0.f,0.f,0.f,0.f,0.f,0.f,0.f};

    f32x16 p0 = __builtin_amdgcn_mfma_f32_32x32x16_bf16(aIn0, bL1, czero, 0, 0, 0);
    f32x16 p1 = __builtin_amdgcn_mfma_f32_32x32x16_bf16(aIn1, bL1, czero, 0, 0, 0);
#pragma unroll
    for (int r = 0; r < 16; ++r) {
        int row = (r & 3) + 8 * (r >> 2) + 4 * h;
        sm[row][j]      = f2bf(fmaxf(p0[r] + bias1, 0.f));
        sm[row + 32][j] = f2bf(fmaxf(p1[r] + bias1, 0.f));
    }
    __syncthreads();

    s16x4 q0 = *(const s16x4*)&sm[j][8 * h];
    s16x4 q1 = *(const s16x4*)&sm[j][8 * h + 4];
    s16x4 q2 = *(const s16x4*)&sm[j][16 + 8 * h];
    s16x4 q3 = *(const s16x4*)&sm[j][16 + 8 * h + 4];
    s16x4 q4 = *(const s16x4*)&sm[32 + j][8 * h];
    s16x4 q5 = *(const s16x4*)&sm[32 + j][8 * h + 4];
    s16x4 q6 = *(const s16x4*)&sm[32 + j][16 + 8 * h];
    s16x4 q7 = *(const s16x4*)&sm[32 + j][16 + 8 * h + 4];
    bf16x8 a0k0 = {q0[0],q0[1],q0[2],q0[3],q1[0],q1[1],q1[2],q1[3]};
    bf16x8 a0k1 = {q2[0],q2[1],q2[2],q2[3],q3[0],q3[1],q3[2],q3[3]};
    bf16x8 a1k0 = {q4[0],q4[1],q4[2],q4[3],q5[0],q5[1],q5[2],q5[3]};
    bf16x8 a1k1 = {q6[0],q6[1],q6[2],q6[3],q7[0],q7[1],q7[2],q7[3]};

    f32x16 acc0 = czero, acc1 = czero;
    acc0 = __builtin_amdgcn_mfma_f32_32x32x16_bf16(a0k0, bk0, acc0, 0, 0, 0);
    acc0 = __builtin_amdgcn_mfma_f32_32x32x16_bf16(a0k1, bk1, acc0, 0, 0, 0);
    acc1 = __builtin_amdgcn_mfma_f32_32x32x16_bf16(a1k0, bk0, acc1, 0, 0, 0);
    acc1 = __builtin_amdgcn_mfma_f32_32x32x16_bf16(a1k1, bk1, acc1, 0, 0, 0);
    __syncthreads();

#pragma unroll
    for (int r = 0; r < 16; ++r) {
        int row = (r & 3) + 8 * (r >> 2) + 4 * h;
        sm[row][j]      = f2bf(fmaxf(acc0[r] + bias2, 0.f));
        sm[row + 32][j] = f2bf(fmaxf(acc1[r] + bias2, 0.f));
    }
    __syncthreads();

    q0 = *(const s16x4*)&sm[j][8 * h];
    q1 = *(const s16x4*)&sm[j][8 * h + 4];
    q2 = *(const s16x4*)&sm[j][16 + 8 * h];
    q3 = *(const s16x4*)&sm[j][16 + 8 * h + 4];
    q4 = *(const s16x4*)&sm[32 + j][8 * h];
    q5 = *(const s16x4*)&sm[32 + j][8 * h + 4];
    q6 = *(const s16x4*)&sm[32 + j][16 + 8 * h];
    q7 = *(const s16x4*)&sm[32 + j][16 + 8 * h + 4];
    bf16x8 m0k0 = {q0[0],q0[1],q0[2],q0[3],q1[0],q1[1],q1[2],q1[3]};
    bf16x8 m0k1 = {q2[0],q2[1],q2[2],q2[3],q3[0],q3[1],q3[2],q3[3]};
    bf16x8 m1k0 = {q4[0],q4[1],q4[2],q4[3],q5[0],q5[1],q5[2],q5[3]};
    bf16x8 m1k1 = {q6[0],q6[1],q6[2],q6[3],q7[0],q7[1],q7[2],q7[3]};

    f32x16 hc0 = czero, hc1 = czero;
    hc0 = __builtin_amdgcn_mfma_f32_32x32x16_bf16(m0k0, hb0, hc0, 0, 0, 0);
    hc0 = __builtin_amdgcn_mfma_f32_32x32x16_bf16(m0k1, hb1, hc0, 0, 0, 0);
    hc1 = __builtin_amdgcn_mfma_f32_32x32x16_bf16(m1k0, hb0, hc1, 0, 0, 0);
    hc1 = __builtin_amdgcn_mfma_f32_32x32x16_bf16(m1k1, hb1, hc1, 0, 0, 0);

    if (j < 4) {
        int cur = sd[4 * h];
        float acc = 0.f;
#pragma unroll
        for (int r = 0; r < 16; ++r) {
            int row = (r & 3) + 8 * (r >> 2) + 4 * h;
            int dr = sd[row];
            if (dr != cur) { atomicAdd(&agg4[cur * 4 + j], acc); acc = 0.f; cur = dr; }
            acc += hc0[r];
        }
#pragma unroll
        for (int r = 0; r < 16; ++r) {
            int row = 32 + (r & 3) + 8 * (r >> 2) + 4 * h;
            int dr = sd[row];
            if (dr != cur) { atomicAdd(&agg4[cur * 4 + j], acc); acc = 0.f; cur = dr; }
            acc += hc1[r];
        }
        atomicAdd(&agg4[cur * 4 + j], acc);
    }
}

__global__ __launch_bounds__(256) void node_kernel(
    const float* __restrict__ h4, const int* __restrict__ off,
    const float* __restrict__ eps,
    const float* __restrict__ mub, const float* __restrict__ vb,
    float* __restrict__ z, float* __restrict__ out)
{
    int n = blockIdx.x * 256 + threadIdx.x;
    if (n >= NN) return;
    float inv = 1.f / fmaxf((float)(off[n + 1] - off[n]), 1.f);
    float4 a = *(const float4*)(h4 + 4 * n);
    float mu0 = a.x * inv + mub[0], mu1 = a.y * inv + mub[1];
    float lv0 = a.z * inv + vb[0],  lv1 = a.w * inv + vb[1];
    out[4 * NN + 2 * n]     = mu0;
    out[4 * NN + 2 * n + 1] = mu1;
    out[6 * NN + 2 * n]     = lv0;
    out[6 * NN + 2 * n + 1] = lv1;
    float2 zz;
    zz.x = mu0 + eps[2 * n]     * expf(0.5f * lv0);
    zz.y = mu1 + eps[2 * n + 1] * expf(0.5f * lv1);
    *(float2*)(z + 2 * n) = zz;
}

__global__ __launch_bounds__(256) void final_kernel(
    const float* __restrict__ o4, const int* __restrict__ off,
    const float* __restrict__ b3, float* __restrict__ out)
{
    int n = blockIdx.x * 256 + threadIdx.x;
    if (n >= NN) return;
    float inv = 1.f / fmaxf((float)(off[n + 1] - off[n]), 1.f);
    float4 a = *(const float4*)(o4 + 4 * n);
    float4 r;
    r.x = a.x * inv + b3[0]; r.y = a.y * inv + b3[1];
    r.z = a.z * inv + b3[2]; r.w = a.w * inv + b3[3];
    *(float4*)(out + 4 * n) = r;
}

extern "C" void kernel_launch(void* const* d_in, const int* in_sizes, int n_in,
                              void* d_out, int out_size, void* d_ws, size_t ws_size,
                              hipStream_t stream)
{
    const float* x     = (const float*)d_in[0];
    const int*   ei    = (const int*)d_in[1];
    const float* eps   = (const float*)d_in[2];
    const float* encW1 = (const float*)d_in[3];
    const float* encb1 = (const float*)d_in[4];
    const float* encW2 = (const float*)d_in[5];
    const float* encb2 = (const float*)d_in[6];
    const float* muW   = (const float*)d_in[7];
    const float* mub   = (const float*)d_in[8];
    const float* vW    = (const float*)d_in[9];
    const float* vb    = (const float*)d_in[10];
    const float* decW1 = (const float*)d_in[11];
    const float* decb1 = (const float*)d_in[12];
    const float* decW2 = (const float*)d_in[13];
    const float* decb2 = (const float*)d_in[14];
    const float* decW3 = (const float*)d_in[15];
    const float* decb3 = (const float*)d_in[16];

    int*   wsI = (int*)d_ws;
    float* wsF = (float*)d_ws;
    dim3 blk(256);
    dim3 egrid(12500);
    dim3 wgrid(50000);
    dim3 ngrid((NN + 255) / 256);

    int2* sd2; int* off; float* h4; float* out4; float* z;

    if (ws_size >= NEED_FAST) {
        // -------- fast path: LDS-privatized two-level bucket sort --------
        sd2  = (int2*)(wsI + WS_SD2F);
        int2* tmp2 = (int2*)(wsI + WS_TMP2);
        off  = wsI + WS_OFFF;
        int* H    = wsI + WS_H;
        int* part = wsI + WS_PARTF;
        h4   = wsF + WS_H4F;
        out4 = wsF + WS_OUT4F;
        z    = wsF + WS_ZF;

        hipMemsetAsync(wsF + WS_H4F, 0, (size_t)800000 * 4, stream);

        bhist<<<dim3(NBH), blk, 0, stream>>>(ei, H);
        spart<<<dim3(NSB), blk, 0, stream>>>(H, NTOT, part);
        spscan<<<dim3(1), blk, 0, stream>>>(part, NSB);
        sfinal<<<dim3(NSB), blk, 0, stream>>>(H, NTOT, part);
        bscatter<<<dim3(NBH), blk, 0, stream>>>(ei, H, tmp2);
        bsort<<<dim3(NBKT), dim3(1024), 0, stream>>>(tmp2, H, sd2, off);
    } else {
        // -------- fallback: round-6 build (global-atomic rank) --------
        sd2  = (int2*)(wsI + FB_SD2);
        off  = wsI + FB_OFF;
        int* cnt  = wsI + FB_CNT;
        int* part = wsI + FB_PART;
        unsigned char* tmp = (unsigned char*)(wsI + FB_TMP);
        h4   = wsF + FB_H4;
        out4 = wsF + FB_OUT4;
        z    = wsF + FB_Z;

        hipMemsetAsync(wsI + FB_CNT, 0, (size_t)NN * 4, stream);
        rank_kernel<<<egrid, blk, 0, stream>>>(ei, cnt, tmp);
        partial_kernel<<<dim3(98), blk, 0, stream>>>(cnt, part);
        scan_partials<<<dim3(1), dim3(128), 0, stream>>>(part, off);
        final_scan<<<dim3(98), blk, 0, stream>>>(cnt, part, off);
        place_kernel<<<egrid, blk, 0, stream>>>(ei, off, tmp, sd2);
        hipMemsetAsync(wsI + FB_H4, 0, (size_t)800000 * 4, stream);
    }

    edge_mfma<<<wgrid, dim3(64), 0, stream>>>(x, 4, encW1, encb1, encW2, encb2,
                                              muW, vW, 0, sd2, h4);
    node_kernel<<<ngrid, blk, 0, stream>>>(h4, off, eps, mub, vb, z, (float*)d_out);
    edge_mfma<<<wgrid, dim3(64), 0, stream>>>(z, 2, decW1, decb1, decW2, decb2,
                                              decW3, decW3, 1, sd2, out4);
    final_kernel<<<ngrid, blk, 0, stream>>>(out4, off, decb3, (float*)d_out);
}

// Round 9
// 201.807 us; speedup vs baseline: 29.8530x; 1.3650x over previous
//
#include <hip/hip_runtime.h>
#include <hip/hip_bf16.h>

#define NN 100000
#define EE 3200000

#define NBKT 196       // coarse buckets: d>>9, 196*512 >= NN
#define NBH  782       // bhist/bscatter blocks: 782*4096 >= EE
#define NTOT (NBKT*NBH)   // 153272
#define NSB  75        // scan blocks: 75*2048 >= NTOT

typedef short bf16x8 __attribute__((ext_vector_type(8)));
typedef short s16x4  __attribute__((ext_vector_type(4)));
typedef float f32x16 __attribute__((ext_vector_type(16)));

// ---- fast-path ws layout (ints), ~56.2 MB ----
#define WS_SD2F  0            // int2[EE]
#define WS_TMP2  6400000      // int2[EE]
#define WS_OFFF  12800000     // int[NN+1]
#define WS_H     12900032     // int[NTOT]
#define WS_PARTF 13053440     // int[128]
#define WS_H4F   13053568     // float[4N]
#define WS_OUT4F 13453568     // float[4N]
#define WS_ZF    13853568     // float[2N]
#define WS_PREP  14053568     // 2560 ints frag + 256 ints bias = 2816
#define NEED_FAST ((size_t)14056384 * 4)

// ---- fallback (round-6) ws layout (ints), ~30.4 MB ----
#define FB_SD2  0
#define FB_OFF  6400000
#define FB_CNT  6500032
#define FB_PART 6600032
#define FB_H4   6600192
#define FB_OUT4 7000192
#define FB_Z    7400192
#define FB_TMP  6600192      // u8[EE] overlay of h4/out4
#define FB_PREP 7600192

// exact round-to-nearest-even f32->bf16 (finite inputs), 4 VALU ops
static __device__ __forceinline__ unsigned short f2bf_fast(float f) {
    unsigned u = __builtin_bit_cast(unsigned, f);
    return (unsigned short)((u + 0x7fffu + ((u >> 16) & 1u)) >> 16);
}

// ================= weight prepack (one block, once per launch) =================
// prep layout (u32): frags [2 variants][5 frags][64 lanes][4 u32] = 2560,
//                    bias  [2 variants][64 lanes][2 f32]          = 256.
__global__ __launch_bounds__(128) void wprep_kernel(
    const float* __restrict__ encW1, const float* __restrict__ encb1,
    const float* __restrict__ encW2, const float* __restrict__ encb2,
    const float* __restrict__ muW,   const float* __restrict__ vW,
    const float* __restrict__ decW1, const float* __restrict__ decb1,
    const float* __restrict__ decW2, const float* __restrict__ decb2,
    const float* __restrict__ decW3, unsigned int* __restrict__ prep)
{
    int t = threadIdx.x;
    int v = t >> 6, l = t & 63;
    int j = l & 31, h = l >> 5;
    const float* W1 = v ? decW1 : encW1;
    const float* b1 = v ? decb1 : encb1;
    const float* W2 = v ? decW2 : encW2;
    const float* b2 = v ? decb2 : encb2;
    int K1 = v ? 4 : 8;
    unsigned short frag[5][8];
#pragma unroll
    for (int i = 0; i < 8; ++i) {
        frag[0][i] = (h == 0 && i < K1) ? f2bf_fast(W1[i * 32 + j]) : (unsigned short)0;
        int k0 = 8 * h + i, k1 = 16 + 8 * h + i;
        frag[1][i] = f2bf_fast(W2[k0 * 32 + j]);
        frag[2][i] = f2bf_fast(W2[k1 * 32 + j]);
        unsigned short w0 = 0, w1 = 0;
        if (j < 4) {
            if (v == 0) {
                w0 = (j < 2) ? f2bf_fast(muW[k0 * 2 + j]) : f2bf_fast(vW[k0 * 2 + (j - 2)]);
                w1 = (j < 2) ? f2bf_fast(muW[k1 * 2 + j]) : f2bf_fast(vW[k1 * 2 + (j - 2)]);
            } else {
                w0 = f2bf_fast(decW3[k0 * 4 + j]);
                w1 = f2bf_fast(decW3[k1 * 4 + j]);
            }
        }
        frag[3][i] = w0; frag[4][i] = w1;
    }
    uint4* fp = (uint4*)prep;
#pragma unroll
    for (int f = 0; f < 5; ++f) {
        uint4 wds;
        wds.x = (unsigned)frag[f][0] | ((unsigned)frag[f][1] << 16);
        wds.y = (unsigned)frag[f][2] | ((unsigned)frag[f][3] << 16);
        wds.z = (unsigned)frag[f][4] | ((unsigned)frag[f][5] << 16);
        wds.w = (unsigned)frag[f][6] | ((unsigned)frag[f][7] << 16);
        fp[(v * 5 + f) * 64 + l] = wds;
    }
    float2 bb; bb.x = b1[j]; bb.y = b2[j];
    ((float2*)(prep + 2560))[v * 64 + l] = bb;
}

// ================= fast-path CSR build (no global atomics) =================

__global__ __launch_bounds__(256) void bhist(
    const int* __restrict__ ei, int* __restrict__ H)
{
    __shared__ int hist[NBKT];
    int t = threadIdx.x;
    if (t < NBKT) hist[t] = 0;
    __syncthreads();
    int base = blockIdx.x * 4096;
#pragma unroll
    for (int k = 0; k < 16; ++k) {
        int e = base + k * 256 + t;
        if (e < EE) atomicAdd(&hist[ei[EE + e] >> 9], 1);
    }
    __syncthreads();
    if (t < NBKT) H[t * NBH + blockIdx.x] = hist[t];
}

__global__ __launch_bounds__(256) void spart(
    const int* __restrict__ H, int n, int* __restrict__ part)
{
    int t = threadIdx.x;
    int base = blockIdx.x * 2048 + t * 8;
    int s = 0;
#pragma unroll
    for (int k = 0; k < 8; ++k) { int i = base + k; if (i < n) s += H[i]; }
    __shared__ int red[256];
    red[t] = s;
    __syncthreads();
    for (int d = 128; d > 0; d >>= 1) {
        if (t < d) red[t] += red[t + d];
        __syncthreads();
    }
    if (t == 0) part[blockIdx.x] = red[0];
}

__global__ __launch_bounds__(256) void spscan(int* __restrict__ part, int np)
{
    __shared__ int sa[256], sbuf[256];
    int t = threadIdx.x;
    int v = (t < np) ? part[t] : 0;
    int *pa = sa, *pb = sbuf;
    pa[t] = v;
    __syncthreads();
    for (int d = 1; d < 256; d <<= 1) {
        pb[t] = pa[t] + ((t >= d) ? pa[t - d] : 0);
        __syncthreads();
        int* tp = pa; pa = pb; pb = tp;
    }
    if (t < np) part[t] = pa[t] - v;   // exclusive
}

__global__ __launch_bounds__(256) void sfinal(
    int* __restrict__ H, int n, const int* __restrict__ part)
{
    int t = threadIdx.x;
    int base = blockIdx.x * 2048 + t * 8;
    int v[8]; int s = 0;
#pragma unroll
    for (int k = 0; k < 8; ++k) { int i = base + k; v[k] = (i < n) ? H[i] : 0; s += v[k]; }
    __shared__ int sa[256], sbuf[256];
    int *pa = sa, *pb = sbuf;
    pa[t] = s;
    __syncthreads();
    for (int d = 1; d < 256; d <<= 1) {
        pb[t] = pa[t] + ((t >= d) ? pa[t - d] : 0);
        __syncthreads();
        int* tp = pa; pa = pb; pb = tp;
    }
    int run = part[blockIdx.x] + pa[t] - s;
#pragma unroll
    for (int k = 0; k < 8; ++k) { int i = base + k; if (i < n) { H[i] = run; run += v[k]; } }
}

__global__ __launch_bounds__(256) void bscatter(
    const int* __restrict__ ei, const int* __restrict__ S, int2* __restrict__ tmp2)
{
    __shared__ int cur[NBKT];
    int t = threadIdx.x;
    if (t < NBKT) cur[t] = S[t * NBH + blockIdx.x];
    __syncthreads();
    int base = blockIdx.x * 4096;
#pragma unroll
    for (int k = 0; k < 16; ++k) {
        int e = base + k * 256 + t;
        if (e < EE) {
            int s = ei[e], d = ei[EE + e];
            int p = atomicAdd(&cur[d >> 9], 1);
            tmp2[p] = make_int2(s, d);
        }
    }
}

__global__ __launch_bounds__(1024) void bsort(
    const int2* __restrict__ tmp2, const int* __restrict__ S,
    int2* __restrict__ sd2, int* __restrict__ off)
{
    int b = blockIdx.x, t = threadIdx.x;
    int bstart = S[b * NBH];
    int bend = (b < NBKT - 1) ? S[(b + 1) * NBH] : EE;
    __shared__ int hist[512], sa[512], sbuf[512];
    if (t < 512) hist[t] = 0;
    __syncthreads();
    for (int e = bstart + t; e < bend; e += 1024)
        atomicAdd(&hist[tmp2[e].y & 511], 1);
    __syncthreads();
    int v = 0;
    if (t < 512) { v = hist[t]; sa[t] = v; }
    __syncthreads();
    int *pa = sa, *pb = sbuf;
    for (int d = 1; d < 512; d <<= 1) {
        if (t < 512) pb[t] = pa[t] + ((t >= d) ? pa[t - d] : 0);
        __syncthreads();
        int* tp = pa; pa = pb; pb = tp;
    }
    if (t < 512) {
        int base = bstart + pa[t] - v;   // exclusive
        int n = b * 512 + t;
        if (n < NN) off[n] = base;
        hist[t] = base;                  // cursor
    }
    if (b == 0 && t == 0) off[NN] = EE;
    __syncthreads();
    for (int e = bstart + t; e < bend; e += 1024) {
        int2 ed = tmp2[e];
        int p = atomicAdd(&hist[ed.y & 511], 1);
        sd2[p] = ed;
    }
}

// ================= fallback CSR build (round-6, proven) =================

__global__ __launch_bounds__(256) void rank_kernel(
    const int* __restrict__ ei, int* __restrict__ cnt, unsigned char* __restrict__ tmp)
{
    int e = blockIdx.x * 256 + threadIdx.x;
    int d = ei[EE + e];
    tmp[e] = (unsigned char)atomicAdd(&cnt[d], 1);
}

__global__ __launch_bounds__(256) void partial_kernel(
    const int* __restrict__ cnt, int* __restrict__ partials)
{
    int i0 = blockIdx.x * 1024 + threadIdx.x * 4;
    int s = 0;
    if (i0 + 3 < NN) {
        int4 v = *(const int4*)(cnt + i0);
        s = v.x + v.y + v.z + v.w;
    } else {
        for (int i = i0; i < NN; ++i) s += cnt[i];
    }
#pragma unroll
    for (int d = 1; d < 64; d <<= 1) s += __shfl_xor(s, d);
    __shared__ int ws_[4];
    if ((threadIdx.x & 63) == 0) ws_[threadIdx.x >> 6] = s;
    __syncthreads();
    if (threadIdx.x == 0) partials[blockIdx.x] = ws_[0] + ws_[1] + ws_[2] + ws_[3];
}

__global__ __launch_bounds__(128) void scan_partials(
    int* __restrict__ partials, int* __restrict__ off)
{
    __shared__ int ls[128];
    int t = threadIdx.x;
    int v = (t < 98) ? partials[t] : 0;
    ls[t] = v;
    __syncthreads();
#pragma unroll
    for (int d = 1; d < 128; d <<= 1) {
        int u = (t >= d) ? ls[t - d] : 0;
        __syncthreads();
        ls[t] += u;
        __syncthreads();
    }
    if (t < 98) partials[t] = ls[t] - v;
    if (t == 127) off[NN] = ls[127];
}

__global__ __launch_bounds__(256) void final_scan(
    const int* __restrict__ cnt, const int* __restrict__ partials, int* __restrict__ off)
{
    int t = threadIdx.x;
    int i0 = blockIdx.x * 1024 + t * 4;
    int4 v = {0, 0, 0, 0};
    if (i0 + 3 < NN) {
        v = *(const int4*)(cnt + i0);
    } else {
        int tv[4] = {0, 0, 0, 0};
        for (int k = 0; k < 4 && i0 + k < NN; ++k) tv[k] = cnt[i0 + k];
        v.x = tv[0]; v.y = tv[1]; v.z = tv[2]; v.w = tv[3];
    }
    int s = v.x + v.y + v.z + v.w;
    __shared__ int ls[256];
    ls[t] = s;
    __syncthreads();
#pragma unroll
    for (int d = 1; d < 256; d <<= 1) {
        int u = (t >= d) ? ls[t - d] : 0;
        __syncthreads();
        ls[t] += u;
        __syncthreads();
    }
    int base = partials[blockIdx.x] + ls[t] - s;
    int4 o;
    o.x = base; o.y = base + v.x; o.z = o.y + v.y; o.w = o.z + v.z;
    if (i0 + 3 < NN) {
        *(int4*)(off + i0) = o;
    } else {
        int oo[4] = {o.x, o.y, o.z, o.w};
        for (int k = 0; k < 4 && i0 + k < NN; ++k) off[i0 + k] = oo[k];
    }
}

__global__ __launch_bounds__(256) void place_kernel(
    const int* __restrict__ ei, const int* __restrict__ off,
    const unsigned char* __restrict__ tmp, int2* __restrict__ sd2)
{
    int e = blockIdx.x * 256 + threadIdx.x;
    int s = ei[e], d = ei[EE + e];
    int p = off[d] + (int)tmp[e];
    sd2[p] = make_int2(s, d);
}

// ================= shared compute kernels =================

// One wave per block; 64 CSR-consecutive edges = two 32-edge M-tiles.
// Weight fragments are prepacked (wfrag/wbias) -> 5x b128 + 1x b64 loads.
__global__ __launch_bounds__(64) void edge_mfma(
    const float* __restrict__ feat, int fdim,
    const uint4* __restrict__ wfrag, const float2* __restrict__ wbias,
    const int2* __restrict__ sd2,
    float* __restrict__ agg4)
{
    __shared__ short sm[64][68];
    __shared__ int   sd[64];
    int l = threadIdx.x;
    int j = l & 31, h = l >> 5;
    int ebase = blockIdx.x * 64;

    int2 me = sd2[ebase + l];
    sd[l] = me.y;
    int s1 = __shfl(me.x, 32 + j);
    int d1 = __shfl(me.y, 32 + j);

    // ---- prepacked B fragments + biases ----
    bf16x8 bL1 = __builtin_bit_cast(bf16x8, wfrag[l]);
    bf16x8 bk0 = __builtin_bit_cast(bf16x8, wfrag[64 + l]);
    bf16x8 bk1 = __builtin_bit_cast(bf16x8, wfrag[128 + l]);
    bf16x8 hb0 = __builtin_bit_cast(bf16x8, wfrag[192 + l]);
    bf16x8 hb1 = __builtin_bit_cast(bf16x8, wfrag[256 + l]);
    float2 bb = wbias[l];
    float bias1 = bb.x, bias2 = bb.y;

    bf16x8 aIn0 = {0,0,0,0,0,0,0,0}, aIn1 = {0,0,0,0,0,0,0,0};
    if (h == 0) {
        int s0 = me.x, d0 = me.y;
        if (fdim == 4) {
            float4 xd = *(const float4*)(feat + 4 * d0);
            float4 xs = *(const float4*)(feat + 4 * s0);
            aIn0[0] = f2bf_fast(xd.x); aIn0[1] = f2bf_fast(xd.y);
            aIn0[2] = f2bf_fast(xd.z); aIn0[3] = f2bf_fast(xd.w);
            aIn0[4] = f2bf_fast(xs.x - xd.x); aIn0[5] = f2bf_fast(xs.y - xd.y);
            aIn0[6] = f2bf_fast(xs.z - xd.z); aIn0[7] = f2bf_fast(xs.w - xd.w);
            xd = *(const float4*)(feat + 4 * d1);
            xs = *(const float4*)(feat + 4 * s1);
            aIn1[0] = f2bf_fast(xd.x); aIn1[1] = f2bf_fast(xd.y);
            aIn1[2] = f2bf_fast(xd.z); aIn1[3] = f2bf_fast(xd.w);
            aIn1[4] = f2bf_fast(xs.x - xd.x); aIn1[5] = f2bf_fast(xs.y - xd.y);
            aIn1[6] = f2bf_fast(xs.z - xd.z); aIn1[7] = f2bf_fast(xs.w - xd.w);
        } else {
            float2 zd = *(const float2*)(feat + 2 * d0);
            float2 zs = *(const float2*)(feat + 2 * s0);
            aIn0[0] = f2bf_fast(zd.x); aIn0[1] = f2bf_fast(zd.y);
            aIn0[2] = f2bf_fast(zs.x - zd.x); aIn0[3] = f2bf_fast(zs.y - zd.y);
            zd = *(const float2*)(feat + 2 * d1);
            zs = *(const float2*)(feat + 2 * s1);
            aIn1[0] = f2bf_fast(zd.x); aIn1[1] = f2bf_fast(zd.y);
            aIn1[2] = f2bf_fast(zs.x - zd.x); aIn1[3] = f2bf_fast(zs.y - zd.y);
        }
    }

    f32x16 czero = {0.f,0.f,0.f,0.f,0.f,0.f,0.f,0.f,0.f,0.f,0.f,0.f,0.f,0.f,0.f,0.f};

    f32x16 p0 = __builtin_amdgcn_mfma_f32_32x32x16_bf16(aIn0, bL1, czero, 0, 0, 0);
    f32x16 p1 = __builtin_amdgcn_mfma_f32_32x32x16_bf16(aIn1, bL1, czero, 0, 0, 0);
#pragma unroll
    for (int r = 0; r < 16; ++r) {
        int row = (r & 3) + 8 * (r >> 2) + 4 * h;
        sm[row][j]      = (short)f2bf_fast(fmaxf(p0[r] + bias1, 0.f));
        sm[row + 32][j] = (short)f2bf_fast(fmaxf(p1[r] + bias1, 0.f));
    }
    __syncthreads();

    s16x4 q0 = *(const s16x4*)&sm[j][8 * h];
    s16x4 q1 = *(const s16x4*)&sm[j][8 * h + 4];
    s16x4 q2 = *(const s16x4*)&sm[j][16 + 8 * h];
    s16x4 q3 = *(const s16x4*)&sm[j][16 + 8 * h + 4];
    s16x4 q4 = *(const s16x4*)&sm[32 + j][8 * h];
    s16x4 q5 = *(const s16x4*)&sm[32 + j][8 * h + 4];
    s16x4 q6 = *(const s16x4*)&sm[32 + j][16 + 8 * h];
    s16x4 q7 = *(const s16x4*)&sm[32 + j][16 + 8 * h + 4];
    bf16x8 a0k0 = {q0[0],q0[1],q0[2],q0[3],q1[0],q1[1],q1[2],q1[3]};
    bf16x8 a0k1 = {q2[0],q2[1],q2[2],q2[3],q3[0],q3[1],q3[2],q3[3]};
    bf16x8 a1k0 = {q4[0],q4[1],q4[2],q4[3],q5[0],q5[1],q5[2],q5[3]};
    bf16x8 a1k1 = {q6[0],q6[1],q6[2],q6[3],q7[0],q7[1],q7[2],q7[3]};

    f32x16 acc0 = czero, acc1 = czero;
    acc0 = __builtin_amdgcn_mfma_f32_32x32x16_bf16(a0k0, bk0, acc0, 0, 0, 0);
    acc0 = __builtin_amdgcn_mfma_f32_32x32x16_bf16(a0k1, bk1, acc0, 0, 0, 0);
    acc1 = __builtin_amdgcn_mfma_f32_32x32x16_bf16(a1k0, bk0, acc1, 0, 0, 0);
    acc1 = __builtin_amdgcn_mfma_f32_32x32x16_bf16(a1k1, bk1, acc1, 0, 0, 0);
    __syncthreads();

#pragma unroll
    for (int r = 0; r < 16; ++r) {
        int row = (r & 3) + 8 * (r >> 2) + 4 * h;
        sm[row][j]      = (short)f2bf_fast(fmaxf(acc0[r] + bias2, 0.f));
        sm[row + 32][j] = (short)f2bf_fast(fmaxf(acc1[r] + bias2, 0.f));
    }
    __syncthreads();

    q0 = *(const s16x4*)&sm[j][8 * h];
    q1 = *(const s16x4*)&sm[j][8 * h + 4];
    q2 = *(const s16x4*)&sm[j][16 + 8 * h];
    q3 = *(const s16x4*)&sm[j][16 + 8 * h + 4];
    q4 = *(const s16x4*)&sm[32 + j][8 * h];
    q5 = *(const s16x4*)&sm[32 + j][8 * h + 4];
    q6 = *(const s16x4*)&sm[32 + j][16 + 8 * h];
    q7 = *(const s16x4*)&sm[32 + j][16 + 8 * h + 4];
    bf16x8 m0k0 = {q0[0],q0[1],q0[2],q0[3],q1[0],q1[1],q1[2],q1[3]};
    bf16x8 m0k1 = {q2[0],q2[1],q2[2],q2[3],q3[0],q3[1],q3[2],q3[3]};
    bf16x8 m1k0 = {q4[0],q4[1],q4[2],q4[3],q5[0],q5[1],q5[2],q5[3]};
    bf16x8 m1k1 = {q6[0],q6[1],q6[2],q6[3],q7[0],q7[1],q7[2],q7[3]};

    f32x16 hc0 = czero, hc1 = czero;
    hc0 = __builtin_amdgcn_mfma_f32_32x32x16_bf16(m0k0, hb0, hc0, 0, 0, 0);
    hc0 = __builtin_amdgcn_mfma_f32_32x32x16_bf16(m0k1, hb1, hc0, 0, 0, 0);
    hc1 = __builtin_amdgcn_mfma_f32_32x32x16_bf16(m1k0, hb0, hc1, 0, 0, 0);
    hc1 = __builtin_amdgcn_mfma_f32_32x32x16_bf16(m1k1, hb1, hc1, 0, 0, 0);

    if (j < 4) {
        int cur = sd[4 * h];
        float acc = 0.f;
#pragma unroll
        for (int r = 0; r < 16; ++r) {
            int row = (r & 3) + 8 * (r >> 2) + 4 * h;
            int dr = sd[row];
            if (dr != cur) { atomicAdd(&agg4[cur * 4 + j], acc); acc = 0.f; cur = dr; }
            acc += hc0[r];
        }
#pragma unroll
        for (int r = 0; r < 16; ++r) {
            int row = 32 + (r & 3) + 8 * (r >> 2) + 4 * h;
            int dr = sd[row];
            if (dr != cur) { atomicAdd(&agg4[cur * 4 + j], acc); acc = 0.f; cur = dr; }
            acc += hc1[r];
        }
        atomicAdd(&agg4[cur * 4 + j], acc);
    }
}

__global__ __launch_bounds__(256) void node_kernel(
    const float* __restrict__ h4, const int* __restrict__ off,
    const float* __restrict__ eps,
    const float* __restrict__ mub, const float* __restrict__ vb,
    float* __restrict__ z, float* __restrict__ out)
{
    int n = blockIdx.x * 256 + threadIdx.x;
    if (n >= NN) return;
    float inv = 1.f / fmaxf((float)(off[n + 1] - off[n]), 1.f);
    float4 a = *(const float4*)(h4 + 4 * n);
    float mu0 = a.x * inv + mub[0], mu1 = a.y * inv + mub[1];
    float lv0 = a.z * inv + vb[0],  lv1 = a.w * inv + vb[1];
    out[4 * NN + 2 * n]     = mu0;
    out[4 * NN + 2 * n + 1] = mu1;
    out[6 * NN + 2 * n]     = lv0;
    out[6 * NN + 2 * n + 1] = lv1;
    float2 zz;
    zz.x = mu0 + eps[2 * n]     * expf(0.5f * lv0);
    zz.y = mu1 + eps[2 * n + 1] * expf(0.5f * lv1);
    *(float2*)(z + 2 * n) = zz;
}

__global__ __launch_bounds__(256) void final_kernel(
    const float* __restrict__ o4, const int* __restrict__ off,
    const float* __restrict__ b3, float* __restrict__ out)
{
    int n = blockIdx.x * 256 + threadIdx.x;
    if (n >= NN) return;
    float inv = 1.f / fmaxf((float)(off[n + 1] - off[n]), 1.f);
    float4 a = *(const float4*)(o4 + 4 * n);
    float4 r;
    r.x = a.x * inv + b3[0]; r.y = a.y * inv + b3[1];
    r.z = a.z * inv + b3[2]; r.w = a.w * inv + b3[3];
    *(float4*)(out + 4 * n) = r;
}

extern "C" void kernel_launch(void* const* d_in, const int* in_sizes, int n_in,
                              void* d_out, int out_size, void* d_ws, size_t ws_size,
                              hipStream_t stream)
{
    const float* x     = (const float*)d_in[0];
    const int*   ei    = (const int*)d_in[1];
    const float* eps   = (const float*)d_in[2];
    const float* encW1 = (const float*)d_in[3];
    const float* encb1 = (const float*)d_in[4];
    const float* encW2 = (const float*)d_in[5];
    const float* encb2 = (const float*)d_in[6];
    const float* muW   = (const float*)d_in[7];
    const float* mub   = (const float*)d_in[8];
    const float* vW    = (const float*)d_in[9];
    const float* vb    = (const float*)d_in[10];
    const float* decW1 = (const float*)d_in[11];
    const float* decb1 = (const float*)d_in[12];
    const float* decW2 = (const float*)d_in[13];
    const float* decb2 = (const float*)d_in[14];
    const float* decW3 = (const float*)d_in[15];
    const float* decb3 = (const float*)d_in[16];

    int*   wsI = (int*)d_ws;
    float* wsF = (float*)d_ws;
    dim3 blk(256);
    dim3 egrid(12500);
    dim3 wgrid(50000);
    dim3 ngrid((NN + 255) / 256);

    int2* sd2; int* off; float* h4; float* out4; float* z; unsigned int* prep;

    if (ws_size >= NEED_FAST) {
        // -------- fast path: LDS-privatized two-level bucket sort --------
        sd2  = (int2*)(wsI + WS_SD2F);
        int2* tmp2 = (int2*)(wsI + WS_TMP2);
        off  = wsI + WS_OFFF;
        int* H    = wsI + WS_H;
        int* part = wsI + WS_PARTF;
        h4   = wsF + WS_H4F;
        out4 = wsF + WS_OUT4F;
        z    = wsF + WS_ZF;
        prep = (unsigned int*)(wsI + WS_PREP);

        hipMemsetAsync(wsF + WS_H4F, 0, (size_t)800000 * 4, stream);
        wprep_kernel<<<dim3(1), dim3(128), 0, stream>>>(
            encW1, encb1, encW2, encb2, muW, vW,
            decW1, decb1, decW2, decb2, decW3, prep);

        bhist<<<dim3(NBH), blk, 0, stream>>>(ei, H);
        spart<<<dim3(NSB), blk, 0, stream>>>(H, NTOT, part);
        spscan<<<dim3(1), blk, 0, stream>>>(part, NSB);
        sfinal<<<dim3(NSB), blk, 0, stream>>>(H, NTOT, part);
        bscatter<<<dim3(NBH), blk, 0, stream>>>(ei, H, tmp2);
        bsort<<<dim3(NBKT), dim3(1024), 0, stream>>>(tmp2, H, sd2, off);
    } else {
        // -------- fallback: round-6 build (global-atomic rank) --------
        sd2  = (int2*)(wsI + FB_SD2);
        off  = wsI + FB_OFF;
        int* cnt  = wsI + FB_CNT;
        int* part = wsI + FB_PART;
        unsigned char* tmp = (unsigned char*)(wsI + FB_TMP);
        h4   = wsF + FB_H4;
        out4 = wsF + FB_OUT4;
        z    = wsF + FB_Z;
        prep = (unsigned int*)(wsI + FB_PREP);

        hipMemsetAsync(wsI + FB_CNT, 0, (size_t)NN * 4, stream);
        wprep_kernel<<<dim3(1), dim3(128), 0, stream>>>(
            encW1, encb1, encW2, encb2, muW, vW,
            decW1, decb1, decW2, decb2, decW3, prep);
        rank_kernel<<<egrid, blk, 0, stream>>>(ei, cnt, tmp);
        partial_kernel<<<dim3(98), blk, 0, stream>>>(cnt, part);
        scan_partials<<<dim3(1), dim3(128), 0, stream>>>(part, off);
        final_scan<<<dim3(98), blk, 0, stream>>>(cnt, part, off);
        place_kernel<<<egrid, blk, 0, stream>>>(ei, off, tmp, sd2);
        hipMemsetAsync(wsI + FB_H4, 0, (size_t)800000 * 4, stream);
    }

    const uint4*  wf = (const uint4*)prep;
    const float2* wb = (const float2*)(prep + 2560);

    edge_mfma<<<wgrid, dim3(64), 0, stream>>>(x, 4, wf, wb, sd2, h4);
    node_kernel<<<ngrid, blk, 0, stream>>>(h4, off, eps, mub, vb, z, (float*)d_out);
    edge_mfma<<<wgrid, dim3(64), 0, stream>>>(z, 2, wf + 5 * 64, wb + 64, sd2, out4);
    final_kernel<<<ngrid, blk, 0, stream>>>(out4, off, decb3, (float*)d_out);
}

// Round 10
// 183.042 us; speedup vs baseline: 32.9135x; 1.1025x over previous
//
#include <hip/hip_runtime.h>
#include <hip/hip_bf16.h>

#define NN 100000
#define EE 3200000

#define NBKT 196       // coarse buckets: d>>9, 196*512 >= NN
#define NBH  782       // bhist/bscatter blocks: 782*4096 >= EE
#define NTOT (NBKT*NBH)   // 153272
#define NSB  75        // scan blocks: 75*2048 >= NTOT

typedef short bf16x8 __attribute__((ext_vector_type(8)));
typedef float f32x16 __attribute__((ext_vector_type(16)));

// ---- fast-path ws layout (ints), ~56.2 MB ----
#define WS_SD2F  0            // int2[EE]
#define WS_TMP2  6400000      // int2[EE]
#define WS_OFFF  12800000     // int[NN+1]
#define WS_H     12900032     // int[NTOT]
#define WS_PARTF 13053440     // int[128]
#define WS_H4F   13053568     // float[4N]
#define WS_OUT4F 13453568     // float[4N]
#define WS_ZF    13853568     // float[2N]
#define WS_PREP  14053568     // 2560 u32 prepacked A-fragments
#define NEED_FAST ((size_t)14056384 * 4)

// ---- fallback (round-6) ws layout (ints), ~30.4 MB ----
#define FB_SD2  0
#define FB_OFF  6400000
#define FB_CNT  6500032
#define FB_PART 6600032
#define FB_H4   6600192
#define FB_OUT4 7000192
#define FB_Z    7400192
#define FB_TMP  6600192      // u8[EE] overlay of h4/out4
#define FB_PREP 7600192

// exact round-to-nearest-even f32->bf16 (finite inputs)
static __device__ __forceinline__ unsigned short f2bf_fast(float f) {
    unsigned u = __builtin_bit_cast(unsigned, f);
    return (unsigned short)((u + 0x7fffu + ((u >> 16) & 1u)) >> 16);
}

// packed f32x2 -> bf16x2 (RNE), single instruction
static __device__ __forceinline__ unsigned cvtpk(float a, float b) {
    unsigned r;
    asm("v_cvt_pk_bf16_f32 %0, %1, %2" : "=v"(r) : "v"(a), "v"(b));
    return r;
}
// swap a.hi-lanes with b.lo-lanes: a' = [a.lo | b.lo], b' = [a.hi | b.hi]
static __device__ __forceinline__ void pl32swap(unsigned &a, unsigned &b) {
    asm("v_permlane32_swap_b32 %0, %1" : "+v"(a), "+v"(b));
}

// ================= weight prepack (once per launch) =================
// prep (u32): A-frags [2 variants][5 frags][64 lanes][4 u32] = 2560.
// f0 = A1 = W1^T rows (+ bias row at k=8), f1/f2 = W2^T (k 0-15, 16-31),
// f3/f4 = Whead^T (k 0-15, 16-31).
__global__ __launch_bounds__(128) void wprep_kernel(
    const float* __restrict__ encW1, const float* __restrict__ encb1,
    const float* __restrict__ encW2,
    const float* __restrict__ muW,   const float* __restrict__ vW,
    const float* __restrict__ decW1, const float* __restrict__ decb1,
    const float* __restrict__ decW2,
    const float* __restrict__ decW3, unsigned int* __restrict__ prep)
{
    int t = threadIdx.x;
    int v = t >> 6, l = t & 63;
    int j = l & 31, h = l >> 5;
    const float* W1 = v ? decW1 : encW1;
    const float* b1 = v ? decb1 : encb1;
    const float* W2 = v ? decW2 : encW2;
    int K1 = v ? 4 : 8;
    unsigned short frag[5][8];
#pragma unroll
    for (int i = 0; i < 8; ++i) {
        unsigned short f0;
        if (h == 0) f0 = (i < K1) ? f2bf_fast(W1[i * 32 + j]) : (unsigned short)0;
        else        f0 = (i == 0) ? f2bf_fast(b1[j]) : (unsigned short)0;
        frag[0][i] = f0;
        int k0 = 8 * h + i, k1 = 16 + 8 * h + i;
        frag[1][i] = f2bf_fast(W2[k0 * 32 + j]);
        frag[2][i] = f2bf_fast(W2[k1 * 32 + j]);
        unsigned short w0 = 0, w1 = 0;
        if (j < 4) {
            if (v == 0) {
                w0 = (j < 2) ? f2bf_fast(muW[k0 * 2 + j]) : f2bf_fast(vW[k0 * 2 + (j - 2)]);
                w1 = (j < 2) ? f2bf_fast(muW[k1 * 2 + j]) : f2bf_fast(vW[k1 * 2 + (j - 2)]);
            } else {
                w0 = f2bf_fast(decW3[k0 * 4 + j]);
                w1 = f2bf_fast(decW3[k1 * 4 + j]);
            }
        }
        frag[3][i] = w0; frag[4][i] = w1;
    }
    uint4* fp = (uint4*)prep;
#pragma unroll
    for (int f = 0; f < 5; ++f) {
        uint4 wds;
        wds.x = (unsigned)frag[f][0] | ((unsigned)frag[f][1] << 16);
        wds.y = (unsigned)frag[f][2] | ((unsigned)frag[f][3] << 16);
        wds.z = (unsigned)frag[f][4] | ((unsigned)frag[f][5] << 16);
        wds.w = (unsigned)frag[f][6] | ((unsigned)frag[f][7] << 16);
        fp[(v * 5 + f) * 64 + l] = wds;
    }
}

// ================= fast-path CSR build (no global atomics) =================

__global__ __launch_bounds__(256) void bhist(
    const int* __restrict__ ei, int* __restrict__ H)
{
    __shared__ int hist[NBKT];
    int t = threadIdx.x;
    if (t < NBKT) hist[t] = 0;
    __syncthreads();
    int base = blockIdx.x * 4096;
#pragma unroll
    for (int k = 0; k < 16; ++k) {
        int e = base + k * 256 + t;
        if (e < EE) atomicAdd(&hist[ei[EE + e] >> 9], 1);
    }
    __syncthreads();
    if (t < NBKT) H[t * NBH + blockIdx.x] = hist[t];
}

__global__ __launch_bounds__(256) void spart(
    const int* __restrict__ H, int n, int* __restrict__ part)
{
    int t = threadIdx.x;
    int base = blockIdx.x * 2048 + t * 8;
    int s = 0;
#pragma unroll
    for (int k = 0; k < 8; ++k) { int i = base + k; if (i < n) s += H[i]; }
    __shared__ int red[256];
    red[t] = s;
    __syncthreads();
    for (int d = 128; d > 0; d >>= 1) {
        if (t < d) red[t] += red[t + d];
        __syncthreads();
    }
    if (t == 0) part[blockIdx.x] = red[0];
}

__global__ __launch_bounds__(256) void spscan(int* __restrict__ part, int np)
{
    __shared__ int sa[256], sbuf[256];
    int t = threadIdx.x;
    int v = (t < np) ? part[t] : 0;
    int *pa = sa, *pb = sbuf;
    pa[t] = v;
    __syncthreads();
    for (int d = 1; d < 256; d <<= 1) {
        pb[t] = pa[t] + ((t >= d) ? pa[t - d] : 0);
        __syncthreads();
        int* tp = pa; pa = pb; pb = tp;
    }
    if (t < np) part[t] = pa[t] - v;   // exclusive
}

__global__ __launch_bounds__(256) void sfinal(
    int* __restrict__ H, int n, const int* __restrict__ part)
{
    int t = threadIdx.x;
    int base = blockIdx.x * 2048 + t * 8;
    int v[8]; int s = 0;
#pragma unroll
    for (int k = 0; k < 8; ++k) { int i = base + k; v[k] = (i < n) ? H[i] : 0; s += v[k]; }
    __shared__ int sa[256], sbuf[256];
    int *pa = sa, *pb = sbuf;
    pa[t] = s;
    __syncthreads();
    for (int d = 1; d < 256; d <<= 1) {
        pb[t] = pa[t] + ((t >= d) ? pa[t - d] : 0);
        __syncthreads();
        int* tp = pa; pa = pb; pb = tp;
    }
    int run = part[blockIdx.x] + pa[t] - s;
#pragma unroll
    for (int k = 0; k < 8; ++k) { int i = base + k; if (i < n) { H[i] = run; run += v[k]; } }
}

__global__ __launch_bounds__(256) void bscatter(
    const int* __restrict__ ei, const int* __restrict__ S, int2* __restrict__ tmp2)
{
    __shared__ int cur[NBKT];
    int t = threadIdx.x;
    if (t < NBKT) cur[t] = S[t * NBH + blockIdx.x];
    __syncthreads();
    int base = blockIdx.x * 4096;
#pragma unroll
    for (int k = 0; k < 16; ++k) {
        int e = base + k * 256 + t;
        if (e < EE) {
            int s = ei[e], d = ei[EE + e];
            int p = atomicAdd(&cur[d >> 9], 1);
            tmp2[p] = make_int2(s, d);
        }
    }
}

__global__ __launch_bounds__(1024) void bsort(
    const int2* __restrict__ tmp2, const int* __restrict__ S,
    int2* __restrict__ sd2, int* __restrict__ off)
{
    int b = blockIdx.x, t = threadIdx.x;
    int bstart = S[b * NBH];
    int bend = (b < NBKT - 1) ? S[(b + 1) * NBH] : EE;
    __shared__ int hist[512], sa[512], sbuf[512];
    if (t < 512) hist[t] = 0;
    __syncthreads();
    for (int e = bstart + t; e < bend; e += 1024)
        atomicAdd(&hist[tmp2[e].y & 511], 1);
    __syncthreads();
    int v = 0;
    if (t < 512) { v = hist[t]; sa[t] = v; }
    __syncthreads();
    int *pa = sa, *pb = sbuf;
    for (int d = 1; d < 512; d <<= 1) {
        if (t < 512) pb[t] = pa[t] + ((t >= d) ? pa[t - d] : 0);
        __syncthreads();
        int* tp = pa; pa = pb; pb = tp;
    }
    if (t < 512) {
        int base = bstart + pa[t] - v;   // exclusive
        int n = b * 512 + t;
        if (n < NN) off[n] = base;
        hist[t] = base;                  // cursor
    }
    if (b == 0 && t == 0) off[NN] = EE;
    __syncthreads();
    for (int e = bstart + t; e < bend; e += 1024) {
        int2 ed = tmp2[e];
        int p = atomicAdd(&hist[ed.y & 511], 1);
        sd2[p] = ed;
    }
}

// ================= fallback CSR build (round-6, proven) =================

__global__ __launch_bounds__(256) void rank_kernel(
    const int* __restrict__ ei, int* __restrict__ cnt, unsigned char* __restrict__ tmp)
{
    int e = blockIdx.x * 256 + threadIdx.x;
    int d = ei[EE + e];
    tmp[e] = (unsigned char)atomicAdd(&cnt[d], 1);
}

__global__ __launch_bounds__(256) void partial_kernel(
    const int* __restrict__ cnt, int* __restrict__ partials)
{
    int i0 = blockIdx.x * 1024 + threadIdx.x * 4;
    int s = 0;
    if (i0 + 3 < NN) {
        int4 v = *(const int4*)(cnt + i0);
        s = v.x + v.y + v.z + v.w;
    } else {
        for (int i = i0; i < NN; ++i) s += cnt[i];
    }
#pragma unroll
    for (int d = 1; d < 64; d <<= 1) s += __shfl_xor(s, d);
    __shared__ int ws_[4];
    if ((threadIdx.x & 63) == 0) ws_[threadIdx.x >> 6] = s;
    __syncthreads();
    if (threadIdx.x == 0) partials[blockIdx.x] = ws_[0] + ws_[1] + ws_[2] + ws_[3];
}

__global__ __launch_bounds__(128) void scan_partials(
    int* __restrict__ partials, int* __restrict__ off)
{
    __shared__ int ls[128];
    int t = threadIdx.x;
    int v = (t < 98) ? partials[t] : 0;
    ls[t] = v;
    __syncthreads();
#pragma unroll
    for (int d = 1; d < 128; d <<= 1) {
        int u = (t >= d) ? ls[t - d] : 0;
        __syncthreads();
        ls[t] += u;
        __syncthreads();
    }
    if (t < 98) partials[t] = ls[t] - v;
    if (t == 127) off[NN] = ls[127];
}

__global__ __launch_bounds__(256) void final_scan(
    const int* __restrict__ cnt, const int* __restrict__ partials, int* __restrict__ off)
{
    int t = threadIdx.x;
    int i0 = blockIdx.x * 1024 + t * 4;
    int4 v = {0, 0, 0, 0};
    if (i0 + 3 < NN) {
        v = *(const int4*)(cnt + i0);
    } else {
        int tv[4] = {0, 0, 0, 0};
        for (int k = 0; k < 4 && i0 + k < NN; ++k) tv[k] = cnt[i0 + k];
        v.x = tv[0]; v.y = tv[1]; v.z = tv[2]; v.w = tv[3];
    }
    int s = v.x + v.y + v.z + v.w;
    __shared__ int ls[256];
    ls[t] = s;
    __syncthreads();
#pragma unroll
    for (int d = 1; d < 256; d <<= 1) {
        int u = (t >= d) ? ls[t - d] : 0;
        __syncthreads();
        ls[t] += u;
        __syncthreads();
    }
    int base = partials[blockIdx.x] + ls[t] - s;
    int4 o;
    o.x = base; o.y = base + v.x; o.z = o.y + v.y; o.w = o.z + v.z;
    if (i0 + 3 < NN) {
        *(int4*)(off + i0) = o;
    } else {
        int oo[4] = {o.x, o.y, o.z, o.w};
        for (int k = 0; k < 4 && i0 + k < NN; ++k) off[i0 + k] = oo[k];
    }
}

__global__ __launch_bounds__(256) void place_kernel(
    const int* __restrict__ ei, const int* __restrict__ off,
    const unsigned char* __restrict__ tmp, int2* __restrict__ sd2)
{
    int e = blockIdx.x * 256 + threadIdx.x;
    int s = ei[e], d = ei[EE + e];
    int p = off[d] + (int)tmp[e];
    sd2[p] = make_int2(s, d);
}

// ================= edge MLP: swapped-operand MFMA, in-register transposes =================
// One wave per block = 64 CSR-consecutive edges = two 32-edge N-tiles.
// A operands = prepacked W^T fragments; B operands built via cvt_pk+permlane32_swap.
__global__ __launch_bounds__(64) void edge_mfma(
    const float* __restrict__ feat, int fdim,
    const uint4* __restrict__ wfrag, const float* __restrict__ b2,
    const int2* __restrict__ sd2,
    float* __restrict__ agg4)
{
    __shared__ int   sd[64];
    __shared__ float sm4[64][5];
    int l = threadIdx.x;
    int h = l >> 5;
    int ebase = blockIdx.x * 64;

    int2 me = sd2[ebase + l];
    sd[l] = me.y;

    // prepacked A fragments
    bf16x8 A1  = __builtin_bit_cast(bf16x8, wfrag[l]);
    bf16x8 A2a = __builtin_bit_cast(bf16x8, wfrag[64 + l]);
    bf16x8 A2b = __builtin_bit_cast(bf16x8, wfrag[128 + l]);
    bf16x8 A3a = __builtin_bit_cast(bf16x8, wfrag[192 + l]);
    bf16x8 A3b = __builtin_bit_cast(bf16x8, wfrag[256 + l]);

    // layer-2 bias as MFMA C-in: reg r -> b2[(r&3)+8*(r>>2)+4h]
    f32x16 cb;
    {
        float4 q0 = *(const float4*)(b2 + 4 * h);
        float4 q1 = *(const float4*)(b2 + 8 + 4 * h);
        float4 q2 = *(const float4*)(b2 + 16 + 4 * h);
        float4 q3 = *(const float4*)(b2 + 24 + 4 * h);
        cb[0] = q0.x; cb[1] = q0.y; cb[2] = q0.z; cb[3] = q0.w;
        cb[4] = q1.x; cb[5] = q1.y; cb[6] = q1.z; cb[7] = q1.w;
        cb[8] = q2.x; cb[9] = q2.y; cb[10] = q2.z; cb[11] = q2.w;
        cb[12] = q3.x; cb[13] = q3.y; cb[14] = q3.z; cb[15] = q3.w;
    }

    // own-edge features -> packed bf16 pairs (all 64 lanes, coalesced-ish)
    unsigned F0 = 0, F1 = 0, F2 = 0, F3 = 0;
    if (fdim == 4) {
        float4 xd = *(const float4*)(feat + 4 * me.y);
        float4 xs = *(const float4*)(feat + 4 * me.x);
        F0 = cvtpk(xd.x, xd.y);
        F1 = cvtpk(xd.z, xd.w);
        F2 = cvtpk(xs.x - xd.x, xs.y - xd.y);
        F3 = cvtpk(xs.z - xd.z, xs.w - xd.w);
    } else {
        float2 zd = *(const float2*)(feat + 2 * me.y);
        float2 zs = *(const float2*)(feat + 2 * me.x);
        F0 = cvtpk(zd.x, zd.y);
        F1 = cvtpk(zs.x - zd.x, zs.y - zd.y);
    }
    // B1 for both tiles via swaps; G0 seeds the bias-one slot (k=8 -> h==1 lanes)
    unsigned G0 = 0x00003F80u, G1 = 0, G2 = 0, G3 = 0;
    pl32swap(F0, G0);  // F0 = [feat(e0..31) | 1.0-slot], G0 = [feat(e32..63) | 1.0-slot]
    pl32swap(F1, G1);
    pl32swap(F2, G2);
    pl32swap(F3, G3);
    bf16x8 B1a = __builtin_bit_cast(bf16x8, make_uint4(F0, F1, F2, F3));
    bf16x8 B1b = __builtin_bit_cast(bf16x8, make_uint4(G0, G1, G2, G3));

    f32x16 czero = {0.f,0.f,0.f,0.f,0.f,0.f,0.f,0.f,0.f,0.f,0.f,0.f,0.f,0.f,0.f,0.f};

    // per-tile pipeline: D1 -> relu/pack -> layer2 (+bias C-in) -> relu/pack -> head
    auto tile = [&](const f32x16& D1, float& o0, float& o1, float& o2, float& o3) {
        unsigned c0 = cvtpk(fmaxf(D1[0], 0.f),  fmaxf(D1[1], 0.f));
        unsigned c1 = cvtpk(fmaxf(D1[2], 0.f),  fmaxf(D1[3], 0.f));
        unsigned c2 = cvtpk(fmaxf(D1[4], 0.f),  fmaxf(D1[5], 0.f));
        unsigned c3 = cvtpk(fmaxf(D1[6], 0.f),  fmaxf(D1[7], 0.f));
        unsigned c4 = cvtpk(fmaxf(D1[8], 0.f),  fmaxf(D1[9], 0.f));
        unsigned c5 = cvtpk(fmaxf(D1[10], 0.f), fmaxf(D1[11], 0.f));
        unsigned c6 = cvtpk(fmaxf(D1[12], 0.f), fmaxf(D1[13], 0.f));
        unsigned c7 = cvtpk(fmaxf(D1[14], 0.f), fmaxf(D1[15], 0.f));
        pl32swap(c0, c2); pl32swap(c1, c3); pl32swap(c4, c6); pl32swap(c5, c7);
        bf16x8 B2a = __builtin_bit_cast(bf16x8, make_uint4(c0, c1, c2, c3));
        bf16x8 B2b = __builtin_bit_cast(bf16x8, make_uint4(c4, c5, c6, c7));
        f32x16 acc = cb;
        acc = __builtin_amdgcn_mfma_f32_32x32x16_bf16(A2a, B2a, acc, 0, 0, 0);
        acc = __builtin_amdgcn_mfma_f32_32x32x16_bf16(A2b, B2b, acc, 0, 0, 0);
        unsigned d0 = cvtpk(fmaxf(acc[0], 0.f),  fmaxf(acc[1], 0.f));
        unsigned d1 = cvtpk(fmaxf(acc[2], 0.f),  fmaxf(acc[3], 0.f));
        unsigned d2 = cvtpk(fmaxf(acc[4], 0.f),  fmaxf(acc[5], 0.f));
        unsigned d3 = cvtpk(fmaxf(acc[6], 0.f),  fmaxf(acc[7], 0.f));
        unsigned d4 = cvtpk(fmaxf(acc[8], 0.f),  fmaxf(acc[9], 0.f));
        unsigned d5 = cvtpk(fmaxf(acc[10], 0.f), fmaxf(acc[11], 0.f));
        unsigned d6 = cvtpk(fmaxf(acc[12], 0.f), fmaxf(acc[13], 0.f));
        unsigned d7 = cvtpk(fmaxf(acc[14], 0.f), fmaxf(acc[15], 0.f));
        pl32swap(d0, d2); pl32swap(d1, d3); pl32swap(d4, d6); pl32swap(d5, d7);
        bf16x8 B3a = __builtin_bit_cast(bf16x8, make_uint4(d0, d1, d2, d3));
        bf16x8 B3b = __builtin_bit_cast(bf16x8, make_uint4(d4, d5, d6, d7));
        f32x16 D3 = czero;
        D3 = __builtin_amdgcn_mfma_f32_32x32x16_bf16(A3a, B3a, D3, 0, 0, 0);
        D3 = __builtin_amdgcn_mfma_f32_32x32x16_bf16(A3b, B3b, D3, 0, 0, 0);
        o0 = D3[0]; o1 = D3[1]; o2 = D3[2]; o3 = D3[3];
    };

    float o0, o1, o2, o3;
    f32x16 D1a = __builtin_amdgcn_mfma_f32_32x32x16_bf16(A1, B1a, czero, 0, 0, 0);
    tile(D1a, o0, o1, o2, o3);
    if (h == 0) { sm4[l][0] = o0; sm4[l][1] = o1; sm4[l][2] = o2; sm4[l][3] = o3; }
    f32x16 D1b = __builtin_amdgcn_mfma_f32_32x32x16_bf16(A1, B1b, czero, 0, 0, 0);
    tile(D1b, o0, o1, o2, o3);
    if (h == 0) { sm4[l + 32][0] = o0; sm4[l + 32][1] = o1; sm4[l + 32][2] = o2; sm4[l + 32][3] = o3; }
    __syncthreads();

    // flush: lane l handles channel c = l&3 over edges [4*seg, 4*seg+4)
    int c = l & 3, e0 = (l >> 2) * 4;
    int cur = sd[e0];
    float acc4 = 0.f;
#pragma unroll
    for (int k = 0; k < 4; ++k) {
        int dr = sd[e0 + k];
        if (dr != cur) { atomicAdd(&agg4[cur * 4 + c], acc4); acc4 = 0.f; cur = dr; }
        acc4 += sm4[e0 + k][c];
    }
    atomicAdd(&agg4[cur * 4 + c], acc4);
}

__global__ __launch_bounds__(256) void node_kernel(
    const float* __restrict__ h4, const int* __restrict__ off,
    const float* __restrict__ eps,
    const float* __restrict__ mub, const float* __restrict__ vb,
    float* __restrict__ z, float* __restrict__ out)
{
    int n = blockIdx.x * 256 + threadIdx.x;
    if (n >= NN) return;
    float inv = 1.f / fmaxf((float)(off[n + 1] - off[n]), 1.f);
    float4 a = *(const float4*)(h4 + 4 * n);
    float mu0 = a.x * inv + mub[0], mu1 = a.y * inv + mub[1];
    float lv0 = a.z * inv + vb[0],  lv1 = a.w * inv + vb[1];
    out[4 * NN + 2 * n]     = mu0;
    out[4 * NN + 2 * n + 1] = mu1;
    out[6 * NN + 2 * n]     = lv0;
    out[6 * NN + 2 * n + 1] = lv1;
    float2 zz;
    zz.x = mu0 + eps[2 * n]     * expf(0.5f * lv0);
    zz.y = mu1 + eps[2 * n + 1] * expf(0.5f * lv1);
    *(float2*)(z + 2 * n) = zz;
}

__global__ __launch_bounds__(256) void final_kernel(
    const float* __restrict__ o4, const int* __restrict__ off,
    const float* __restrict__ b3, float* __restrict__ out)
{
    int n = blockIdx.x * 256 + threadIdx.x;
    if (n >= NN) return;
    float inv = 1.f / fmaxf((float)(off[n + 1] - off[n]), 1.f);
    float4 a = *(const float4*)(o4 + 4 * n);
    float4 r;
    r.x = a.x * inv + b3[0]; r.y = a.y * inv + b3[1];
    r.z = a.z * inv + b3[2]; r.w = a.w * inv + b3[3];
    *(float4*)(out + 4 * n) = r;
}

extern "C" void kernel_launch(void* const* d_in, const int* in_sizes, int n_in,
                              void* d_out, int out_size, void* d_ws, size_t ws_size,
                              hipStream_t stream)
{
    const float* x     = (const float*)d_in[0];
    const int*   ei    = (const int*)d_in[1];
    const float* eps   = (const float*)d_in[2];
    const float* encW1 = (const float*)d_in[3];
    const float* encb1 = (const float*)d_in[4];
    const float* encW2 = (const float*)d_in[5];
    const float* encb2 = (const float*)d_in[6];
    const float* muW   = (const float*)d_in[7];
    const float* mub   = (const float*)d_in[8];
    const float* vW    = (const float*)d_in[9];
    const float* vb    = (const float*)d_in[10];
    const float* decW1 = (const float*)d_in[11];
    const float* decb1 = (const float*)d_in[12];
    const float* decW2 = (const float*)d_in[13];
    const float* decb2 = (const float*)d_in[14];
    const float* decW3 = (const float*)d_in[15];
    const float* decb3 = (const float*)d_in[16];

    int*   wsI = (int*)d_ws;
    float* wsF = (float*)d_ws;
    dim3 blk(256);
    dim3 egrid(12500);
    dim3 wgrid(50000);
    dim3 ngrid((NN + 255) / 256);

    int2* sd2; int* off; float* h4; float* out4; float* z; unsigned int* prep;

    if (ws_size >= NEED_FAST) {
        // -------- fast path: LDS-privatized two-level bucket sort --------
        sd2  = (int2*)(wsI + WS_SD2F);
        int2* tmp2 = (int2*)(wsI + WS_TMP2);
        off  = wsI + WS_OFFF;
        int* H    = wsI + WS_H;
        int* part = wsI + WS_PARTF;
        h4   = wsF + WS_H4F;
        out4 = wsF + WS_OUT4F;
        z    = wsF + WS_ZF;
        prep = (unsigned int*)(wsI + WS_PREP);

        hipMemsetAsync(wsF + WS_H4F, 0, (size_t)800000 * 4, stream);
        wprep_kernel<<<dim3(1), dim3(128), 0, stream>>>(
            encW1, encb1, encW2, muW, vW,
            decW1, decb1, decW2, decW3, prep);

        bhist<<<dim3(NBH), blk, 0, stream>>>(ei, H);
        spart<<<dim3(NSB), blk, 0, stream>>>(H, NTOT, part);
        spscan<<<dim3(1), blk, 0, stream>>>(part, NSB);
        sfinal<<<dim3(NSB), blk, 0, stream>>>(H, NTOT, part);
        bscatter<<<dim3(NBH), blk, 0, stream>>>(ei, H, tmp2);
        bsort<<<dim3(NBKT), dim3(1024), 0, stream>>>(tmp2, H, sd2, off);
    } else {
        // -------- fallback: round-6 build (global-atomic rank) --------
        sd2  = (int2*)(wsI + FB_SD2);
        off  = wsI + FB_OFF;
        int* cnt  = wsI + FB_CNT;
        int* part = wsI + FB_PART;
        unsigned char* tmp = (unsigned char*)(wsI + FB_TMP);
        h4   = wsF + FB_H4;
        out4 = wsF + FB_OUT4;
        z    = wsF + FB_Z;
        prep = (unsigned int*)(wsI + FB_PREP);

        hipMemsetAsync(wsI + FB_CNT, 0, (size_t)NN * 4, stream);
        wprep_kernel<<<dim3(1), dim3(128), 0, stream>>>(
            encW1, encb1, encW2, muW, vW,
            decW1, decb1, decW2, decW3, prep);
        rank_kernel<<<egrid, blk, 0, stream>>>(ei, cnt, tmp);
        partial_kernel<<<dim3(98), blk, 0, stream>>>(cnt, part);
        scan_partials<<<dim3(1), dim3(128), 0, stream>>>(part, off);
        final_scan<<<dim3(98), blk, 0, stream>>>(cnt, part, off);
        place_kernel<<<egrid, blk, 0, stream>>>(ei, off, tmp, sd2);
        hipMemsetAsync(wsI + FB_H4, 0, (size_t)800000 * 4, stream);
    }

    const uint4* wf = (const uint4*)prep;

    edge_mfma<<<wgrid, dim3(64), 0, stream>>>(x, 4, wf, encb2, sd2, h4);
    node_kernel<<<ngrid, blk, 0, stream>>>(h4, off, eps, mub, vb, z, (float*)d_out);
    edge_mfma<<<wgrid, dim3(64), 0, stream>>>(z, 2, wf + 5 * 64, decb2, sd2, out4);
    final_kernel<<<ngrid, blk, 0, stream>>>(out4, off, decb3, (float*)d_out);
}